// Round 2
// baseline (288.129 us; speedup 1.0000x reference)
//
#include <hip/hip_runtime.h>

typedef short short8 __attribute__((ext_vector_type(8)));
typedef short short4v __attribute__((ext_vector_type(4)));
typedef float f32x4 __attribute__((ext_vector_type(4)));

#define EPS_NUMER_F 1e-8f
#define EPS_D2_F 1e-12f

// ---- constants for this problem ----
#define BB 128          // batch
#define TT 128          // time
#define DD 1024         // feature dim
#define CHW 3072        // C*H*W
#define NC 10           // classes
#define MM (BB * TT)    // 16384 GEMM rows

static __device__ __forceinline__ short f2bf(float x) {
  // round-to-nearest-even bf16 (values here are finite/sane, no NaN path)
  unsigned int u = __float_as_uint(x);
  u = (u + 0x7fffu + ((u >> 16) & 1u)) >> 16;
  return (short)u;
}
static __device__ __forceinline__ float bf2f(short x) {
  return __uint_as_float(((unsigned int)(unsigned short)x) << 16);
}

// ---------------------------------------------------------------------------
// Kernel 1: W_fe (3072 x 1024 f32, row-major K x N) -> Wt (1024 x 3072 bf16)
// ---------------------------------------------------------------------------
__global__ __launch_bounds__(256) void k_transpose_w(const float* __restrict__ W,
                                                     short* __restrict__ Wt) {
  __shared__ float tile[32][33];
  const int n0 = blockIdx.x * 32;   // over N = 1024
  const int k0 = blockIdx.y * 32;   // over K = 3072
  const int tx = threadIdx.x & 31;
  const int ty = threadIdx.x >> 5;  // 0..7
#pragma unroll
  for (int i = 0; i < 32; i += 8)
    tile[ty + i][tx] = W[(size_t)(k0 + ty + i) * DD + (n0 + tx)];
  __syncthreads();
#pragma unroll
  for (int i = 0; i < 32; i += 8)
    Wt[(size_t)(n0 + ty + i) * CHW + (k0 + tx)] = f2bf(tile[tx][ty + i]);
}

// ---------------------------------------------------------------------------
// Kernel 2: F(bf16, 16384 x 1024) = X(f32) @ W + b   via mfma_f32_16x16x32_bf16
// 128x128 tile, BK=32, 256 threads = 4 waves (2x2 of 64x64), reg-staged A with
// inline f32->bf16 convert; LDS rows padded to 40 shorts (80B).
// ---------------------------------------------------------------------------
__global__ __launch_bounds__(256) void k_gemm_feats(const float* __restrict__ X,
                                                    const short* __restrict__ Wt,
                                                    const float* __restrict__ bias,
                                                    short* __restrict__ F) {
  __shared__ short As[128][40];
  __shared__ short Bs[128][40];

  // XCD-aware swizzle: 1024 blocks, 8 XCDs, 128 contiguous ids per XCD.
  const int bid = blockIdx.x;
  const int id = (bid & 7) * 128 + (bid >> 3);
  const int bm = (id >> 3) << 7;   // 0..16256
  const int bn = (id & 7) << 7;    // 0..896

  const int tid = threadIdx.x;
  const int lane = tid & 63;
  const int wid = tid >> 6;
  const int wr = (wid >> 1) * 64;
  const int wc = (wid & 1) * 64;

  f32x4 acc[4][4] = {};

  const int fr = lane & 15;
  const int fk = (lane >> 4) << 3;

  for (int k0 = 0; k0 < CHW; k0 += 32) {
    // stage A: 128 rows x 32 k, f32 -> bf16. 1024 float4 loads: idx>>3 = row,
    // (idx&7)*4 = k offset.
#pragma unroll
    for (int i = 0; i < 4; ++i) {
      int idx = tid + (i << 8);
      int row = idx >> 3;
      int kc = (idx & 7) << 2;
      float4 v = *reinterpret_cast<const float4*>(X + (size_t)(bm + row) * CHW + (k0 + kc));
      short4v s;
      s[0] = f2bf(v.x); s[1] = f2bf(v.y); s[2] = f2bf(v.z); s[3] = f2bf(v.w);
      *reinterpret_cast<short4v*>(&As[row][kc]) = s;
    }
    // stage B: 128 rows (n) x 32 k bf16. 512 short8 loads: 4 loads per row.
#pragma unroll
    for (int i = 0; i < 2; ++i) {
      int idx = tid + (i << 8);
      int row = idx >> 2;           // 0..127  (FIXED: was idx>>1 -> OOB)
      int kc = (idx & 3) << 3;      // 0,8,16,24 (FIXED: was missing 8-15,24-31)
      short8 v = *reinterpret_cast<const short8*>(Wt + (size_t)(bn + row) * CHW + (k0 + kc));
      *reinterpret_cast<short8*>(&Bs[row][kc]) = v;
    }
    __syncthreads();

    short8 af[4], bfv[4];
#pragma unroll
    for (int mi = 0; mi < 4; ++mi)
      af[mi] = *reinterpret_cast<const short8*>(&As[wr + mi * 16 + fr][fk]);
#pragma unroll
    for (int ni = 0; ni < 4; ++ni)
      bfv[ni] = *reinterpret_cast<const short8*>(&Bs[wc + ni * 16 + fr][fk]);
#pragma unroll
    for (int mi = 0; mi < 4; ++mi)
#pragma unroll
      for (int ni = 0; ni < 4; ++ni)
        acc[mi][ni] = __builtin_amdgcn_mfma_f32_16x16x32_bf16(af[mi], bfv[ni], acc[mi][ni], 0, 0, 0);
    __syncthreads();
  }

  // epilogue: C/D layout col = lane&15, row = (lane>>4)*4 + q  [verified m89/m91]
  const int cc = lane & 15;
  const int crr = (lane >> 4) << 2;
#pragma unroll
  for (int ni = 0; ni < 4; ++ni) {
    int col = bn + wc + ni * 16 + cc;
    float bv = bias[col];
#pragma unroll
    for (int mi = 0; mi < 4; ++mi) {
      int row0 = bm + wr + mi * 16 + crr;
#pragma unroll
      for (int q = 0; q < 4; ++q)
        F[(size_t)(row0 + q) * DD + col] = f2bf(acc[mi][ni][q] + bv);
    }
  }
}

// ---------------------------------------------------------------------------
// Kernel 3: per (batch, t-half): Gram via MFMA -> d2 -> sims -> causal numer
// -> pow/normalize -> out.  Grid = 256 blocks (b = bid>>1, half = bid&1),
// 256 threads = 4 waves; block computes sims[s=0..127][t' = half*64 .. +64).
// ---------------------------------------------------------------------------
__global__ __launch_bounds__(256) void k_batch_sims(const short* __restrict__ F,
                                                    const float* __restrict__ teach,
                                                    const float* __restrict__ cptr,
                                                    const float* __restrict__ gptr,
                                                    float* __restrict__ out) {
  __shared__ short ftile[128][40];
  __shared__ float simsT[64][129];   // [t_local][s]
  __shared__ float sqv[128];
  __shared__ float sqp[256];
  __shared__ float teach_s[128][NC];
  __shared__ float numer[64][NC];
  __shared__ float rsum[64];

  const int b = blockIdx.x >> 1;
  const int half = blockIdx.x & 1;
  const int tid = threadIdx.x;
  const int lane = tid & 63;
  const int w = tid >> 6;
  const size_t fbase = (size_t)b * TT * DD;

  // teaching signal -> LDS
  for (int idx = tid; idx < TT * NC; idx += 256)
    teach_s[idx / NC][idx % NC] = teach[(size_t)b * TT * NC + idx];

  // sq[s] = sum_k f[s][k]^2 (2 threads per row)
  {
    int row = tid >> 1;
    int kh = (tid & 1) << 9;  // 0 or 512
    const short* fp = F + fbase + (size_t)row * DD + kh;
    float s = 0.f;
    for (int k = 0; k < 512; k += 8) {
      short8 v = *reinterpret_cast<const short8*>(fp + k);
#pragma unroll
      for (int j = 0; j < 8; ++j) { float x = bf2f(v[j]); s += x * x; }
    }
    sqp[tid] = s;
  }
  __syncthreads();
  if (tid < 128) sqv[tid] = sqp[2 * tid] + sqp[2 * tid + 1];
  __syncthreads();

  // Gram: G[s][t'] = f_b @ f_b[t-half]^T, K-loop over D
  f32x4 acc[2][4] = {};
  const int fr = lane & 15;
  const int fk = (lane >> 4) << 3;
  for (int k0 = 0; k0 < DD; k0 += 32) {
#pragma unroll
    for (int i = 0; i < 2; ++i) {
      int idx = tid + (i << 8);
      int row = idx >> 2;           // 0..127  (FIXED: was idx>>1 -> OOB)
      int kc = (idx & 3) << 3;      // 0,8,16,24 (FIXED)
      short8 v = *reinterpret_cast<const short8*>(F + fbase + (size_t)row * DD + (k0 + kc));
      *reinterpret_cast<short8*>(&ftile[row][kc]) = v;
    }
    __syncthreads();
    short8 af[2], bfv[4];
#pragma unroll
    for (int mi = 0; mi < 2; ++mi)
      af[mi] = *reinterpret_cast<const short8*>(&ftile[w * 32 + mi * 16 + fr][fk]);
#pragma unroll
    for (int ni = 0; ni < 4; ++ni)
      bfv[ni] = *reinterpret_cast<const short8*>(&ftile[half * 64 + ni * 16 + fr][fk]);
#pragma unroll
    for (int mi = 0; mi < 2; ++mi)
#pragma unroll
      for (int ni = 0; ni < 4; ++ni)
        acc[mi][ni] = __builtin_amdgcn_mfma_f32_16x16x32_bf16(af[mi], bfv[ni], acc[mi][ni], 0, 0, 0);
    __syncthreads();
  }

  // sims with causal mask (s < t strictly), write transposed for row reads
  const float c0 = cptr[0];
  const int cc = lane & 15;
  const int crr = (lane >> 4) << 2;
#pragma unroll
  for (int mi = 0; mi < 2; ++mi) {
#pragma unroll
    for (int ni = 0; ni < 4; ++ni) {
#pragma unroll
      for (int q = 0; q < 4; ++q) {
        int s_g = w * 32 + mi * 16 + crr + q;
        int tl = ni * 16 + cc;
        int t_g = half * 64 + tl;
        float g = acc[mi][ni][q];
        float d2 = sqv[s_g] + sqv[t_g] - 2.0f * g;
        d2 = fmaxf(d2, EPS_D2_F);
        float dist = sqrtf(sqrtf(d2));
        simsT[tl][s_g] = (s_g < t_g) ? expf(-c0 * dist) : 0.0f;
      }
    }
  }
  __syncthreads();

  // numers[t'][c] = eps + sum_s simsT[t'][s] * teach[s][c]; then ^gamma
  const float gam = gptr[0];
  for (int idx = tid; idx < 64 * NC; idx += 256) {
    int tl = idx / NC, c = idx % NC;
    float s = 0.f;
#pragma unroll 4
    for (int si = 0; si < TT; ++si)
      s += simsT[tl][si] * teach_s[si][c];
    float v = EPS_NUMER_F + s;
    numer[tl][c] = (gam == 1.0f) ? v : powf(v, gam);
  }
  __syncthreads();
  if (tid < 64) {
    float s = 0.f;
#pragma unroll
    for (int c = 0; c < NC; ++c) s += numer[tid][c];
    rsum[tid] = s;
  }
  __syncthreads();
  for (int idx = tid; idx < 64 * NC; idx += 256) {
    int tl = idx / NC, c = idx % NC;
    int t_g = half * 64 + tl;
    float v = numer[tl][c] / rsum[tl];
    if (t_g == 0) v = EPS_NUMER_F;
    out[(size_t)b * TT * NC + (size_t)t_g * NC + c] = v;
  }
}

// ---------------------------------------------------------------------------
extern "C" void kernel_launch(void* const* d_in, const int* in_sizes, int n_in,
                              void* d_out, int out_size, void* d_ws, size_t ws_size,
                              hipStream_t stream) {
  // inputs (setup_inputs order): responses_t, data_t, teaching_signal_t,
  //                              W_fe, b_fe, c, gamma
  const float* data = (const float*)d_in[1];
  const float* teach = (const float*)d_in[2];
  const float* Wfe = (const float*)d_in[3];
  const float* bfe = (const float*)d_in[4];
  const float* cp = (const float*)d_in[5];
  const float* gp = (const float*)d_in[6];
  float* outp = (float*)d_out;

  char* ws = (char*)d_ws;
  short* Wt = (short*)ws;                            // 1024*3072*2 = 6.3 MB
  short* F = (short*)(ws + (size_t)8 * 1024 * 1024); // 16384*1024*2 = 33.6 MB

  k_transpose_w<<<dim3(DD / 32, CHW / 32), 256, 0, stream>>>(Wfe, Wt);
  k_gemm_feats<<<dim3((MM / 128) * (DD / 128)), 256, 0, stream>>>(data, Wt, bfe, F);
  k_batch_sims<<<dim3(BB * 2), 256, 0, stream>>>(F, teach, cp, gp, outp);
}

// Round 3
// 226.055 us; speedup vs baseline: 1.2746x; 1.2746x over previous
//
#include <hip/hip_runtime.h>

typedef short short8 __attribute__((ext_vector_type(8)));
typedef short short4v __attribute__((ext_vector_type(4)));
typedef float f32x4 __attribute__((ext_vector_type(4)));

#define EPS_NUMER_F 1e-8f
#define EPS_D2_F 1e-12f

#define BB 128
#define TT 128
#define DD 1024
#define CHW 3072
#define NC 10
#define MM (BB * TT)

#define GLOAD_LDS16(g, l)                                              \
  __builtin_amdgcn_global_load_lds(                                    \
      (const __attribute__((address_space(1))) void*)(g),              \
      (__attribute__((address_space(3))) void*)(l), 16, 0, 0)

static __device__ __forceinline__ short f2bf(float x) {
  unsigned int u = __float_as_uint(x);
  u = (u + 0x7fffu + ((u >> 16) & 1u)) >> 16;
  return (short)u;
}
static __device__ __forceinline__ float bf2f(short x) {
  return __uint_as_float(((unsigned int)(unsigned short)x) << 16);
}

// ---------------------------------------------------------------------------
// X (16384 x 3072 f32) -> Xb (bf16), 8 elems/thread, exact grid
// ---------------------------------------------------------------------------
__global__ __launch_bounds__(256) void k_convert_x(const float* __restrict__ X,
                                                   short* __restrict__ Xb) {
  size_t i = ((size_t)blockIdx.x * 256 + threadIdx.x) * 8;
  float4 a = *reinterpret_cast<const float4*>(X + i);
  float4 b = *reinterpret_cast<const float4*>(X + i + 4);
  short8 s;
  s[0] = f2bf(a.x); s[1] = f2bf(a.y); s[2] = f2bf(a.z); s[3] = f2bf(a.w);
  s[4] = f2bf(b.x); s[5] = f2bf(b.y); s[6] = f2bf(b.z); s[7] = f2bf(b.w);
  *reinterpret_cast<short8*>(Xb + i) = s;
}

// ---------------------------------------------------------------------------
// W_fe (3072 x 1024 f32, K x N) -> Wt (1024 x 3072 bf16, N x K)
// ---------------------------------------------------------------------------
__global__ __launch_bounds__(256) void k_transpose_w(const float* __restrict__ W,
                                                     short* __restrict__ Wt) {
  __shared__ float tile[32][33];
  const int n0 = blockIdx.x * 32;
  const int k0 = blockIdx.y * 32;
  const int tx = threadIdx.x & 31;
  const int ty = threadIdx.x >> 5;
#pragma unroll
  for (int i = 0; i < 32; i += 8)
    tile[ty + i][tx] = W[(size_t)(k0 + ty + i) * DD + (n0 + tx)];
  __syncthreads();
#pragma unroll
  for (int i = 0; i < 32; i += 8)
    Wt[(size_t)(n0 + ty + i) * CHW + (k0 + tx)] = f2bf(tile[tx][ty + i]);
}

// ---------------------------------------------------------------------------
// m97-structure GEMM: F = Xb @ Wt^T + b.  128x128 tile, BK=32, 4 waves,
// global_load_lds width=16 for both operands, linear LDS [128][32].
// ---------------------------------------------------------------------------
__global__ __launch_bounds__(256) void k_gemm_feats(const short* __restrict__ Xb,
                                                    const short* __restrict__ Wt,
                                                    const float* __restrict__ bias,
                                                    short* __restrict__ F) {
  __shared__ short As[128 * 32];
  __shared__ short Bs[128 * 32];

  const int bid = blockIdx.x;
  const int id = (bid & 7) * 128 + (bid >> 3);  // 1024 blocks, 8 XCDs
  const int bm = (id >> 3) << 7;
  const int bn = (id & 7) << 7;

  const int tid = threadIdx.x;
  const int lane = tid & 63;
  const int wid = tid >> 6;
  const int wr = (wid >> 1) * 64;
  const int wc = (wid & 1) * 64;

  f32x4 acc[4][4] = {};
  const int fr = lane & 15;
  const int fk = (lane >> 4) << 3;

  // staging geometry: tile = 8 chunks of 1024B (16 rows); wave w, issue i
  // covers chunk i*4+w; lane l covers shorts [chunk*512 + l*8, +8)
  //   row = chunk*16 + l/4, col = (l&3)*8  (verified: row*32+col == chunk*512+l*8)
  const int srow0 = wid * 16 + (lane >> 2);        // chunk = wid
  const int srow1 = (4 + wid) * 16 + (lane >> 2);  // chunk = 4+wid
  const int scol = (lane & 3) << 3;
  const short* aSrc0 = Xb + (size_t)(bm + srow0) * CHW + scol;
  const short* aSrc1 = Xb + (size_t)(bm + srow1) * CHW + scol;
  const short* bSrc0 = Wt + (size_t)(bn + srow0) * CHW + scol;
  const short* bSrc1 = Wt + (size_t)(bn + srow1) * CHW + scol;
  short* aDst0 = &As[wid * 512];        // wave-uniform LDS base
  short* aDst1 = &As[(4 + wid) * 512];
  short* bDst0 = &Bs[wid * 512];
  short* bDst1 = &Bs[(4 + wid) * 512];

  for (int k0 = 0; k0 < CHW; k0 += 32) {
    GLOAD_LDS16(aSrc0 + k0, aDst0);
    GLOAD_LDS16(aSrc1 + k0, aDst1);
    GLOAD_LDS16(bSrc0 + k0, bDst0);
    GLOAD_LDS16(bSrc1 + k0, bDst1);
    __syncthreads();  // compiler drains vmcnt before barrier

    short8 af[4], bfv[4];
#pragma unroll
    for (int mi = 0; mi < 4; ++mi)
      af[mi] = *reinterpret_cast<const short8*>(&As[(wr + mi * 16 + fr) * 32 + fk]);
#pragma unroll
    for (int ni = 0; ni < 4; ++ni)
      bfv[ni] = *reinterpret_cast<const short8*>(&Bs[(wc + ni * 16 + fr) * 32 + fk]);
#pragma unroll
    for (int mi = 0; mi < 4; ++mi)
#pragma unroll
      for (int ni = 0; ni < 4; ++ni)
        acc[mi][ni] = __builtin_amdgcn_mfma_f32_16x16x32_bf16(af[mi], bfv[ni], acc[mi][ni], 0, 0, 0);
    __syncthreads();
  }

  const int cc = lane & 15;
  const int crr = (lane >> 4) << 2;
#pragma unroll
  for (int ni = 0; ni < 4; ++ni) {
    int col = bn + wc + ni * 16 + cc;
    float bv = bias[col];
#pragma unroll
    for (int mi = 0; mi < 4; ++mi) {
      int row0 = bm + wr + mi * 16 + crr;
#pragma unroll
      for (int q = 0; q < 4; ++q)
        F[(size_t)(row0 + q) * DD + col] = f2bf(acc[mi][ni][q] + bv);
    }
  }
}

// ---------------------------------------------------------------------------
// Fallback GEMM (round-2, reg-staged inline convert) if ws too small for Xb
// ---------------------------------------------------------------------------
__global__ __launch_bounds__(256) void k_gemm_feats_rs(const float* __restrict__ X,
                                                       const short* __restrict__ Wt,
                                                       const float* __restrict__ bias,
                                                       short* __restrict__ F) {
  __shared__ short As[128][40];
  __shared__ short Bs[128][40];
  const int bid = blockIdx.x;
  const int id = (bid & 7) * 128 + (bid >> 3);
  const int bm = (id >> 3) << 7;
  const int bn = (id & 7) << 7;
  const int tid = threadIdx.x;
  const int lane = tid & 63;
  const int wid = tid >> 6;
  const int wr = (wid >> 1) * 64;
  const int wc = (wid & 1) * 64;
  f32x4 acc[4][4] = {};
  const int fr = lane & 15;
  const int fk = (lane >> 4) << 3;
  for (int k0 = 0; k0 < CHW; k0 += 32) {
#pragma unroll
    for (int i = 0; i < 4; ++i) {
      int idx = tid + (i << 8);
      int row = idx >> 3;
      int kc = (idx & 7) << 2;
      float4 v = *reinterpret_cast<const float4*>(X + (size_t)(bm + row) * CHW + (k0 + kc));
      short4v s;
      s[0] = f2bf(v.x); s[1] = f2bf(v.y); s[2] = f2bf(v.z); s[3] = f2bf(v.w);
      *reinterpret_cast<short4v*>(&As[row][kc]) = s;
    }
#pragma unroll
    for (int i = 0; i < 2; ++i) {
      int idx = tid + (i << 8);
      int row = idx >> 2;
      int kc = (idx & 3) << 3;
      short8 v = *reinterpret_cast<const short8*>(Wt + (size_t)(bn + row) * CHW + (k0 + kc));
      *reinterpret_cast<short8*>(&Bs[row][kc]) = v;
    }
    __syncthreads();
    short8 af[4], bfv[4];
#pragma unroll
    for (int mi = 0; mi < 4; ++mi)
      af[mi] = *reinterpret_cast<const short8*>(&As[wr + mi * 16 + fr][fk]);
#pragma unroll
    for (int ni = 0; ni < 4; ++ni)
      bfv[ni] = *reinterpret_cast<const short8*>(&Bs[wc + ni * 16 + fr][fk]);
#pragma unroll
    for (int mi = 0; mi < 4; ++mi)
#pragma unroll
      for (int ni = 0; ni < 4; ++ni)
        acc[mi][ni] = __builtin_amdgcn_mfma_f32_16x16x32_bf16(af[mi], bfv[ni], acc[mi][ni], 0, 0, 0);
    __syncthreads();
  }
  const int cc = lane & 15;
  const int crr = (lane >> 4) << 2;
#pragma unroll
  for (int ni = 0; ni < 4; ++ni) {
    int col = bn + wc + ni * 16 + cc;
    float bv = bias[col];
#pragma unroll
    for (int mi = 0; mi < 4; ++mi) {
      int row0 = bm + wr + mi * 16 + crr;
#pragma unroll
      for (int q = 0; q < 4; ++q)
        F[(size_t)(row0 + q) * DD + col] = f2bf(acc[mi][ni][q] + bv);
    }
  }
}

// ---------------------------------------------------------------------------
// Kernel 3: per (batch, t-half): Gram via MFMA -> d2 -> sims -> causal numer
// -> pow/normalize -> out.  (unchanged from round 2 — passed, ~µs-scale)
// ---------------------------------------------------------------------------
__global__ __launch_bounds__(256) void k_batch_sims(const short* __restrict__ F,
                                                    const float* __restrict__ teach,
                                                    const float* __restrict__ cptr,
                                                    const float* __restrict__ gptr,
                                                    float* __restrict__ out) {
  __shared__ short ftile[128][40];
  __shared__ float simsT[64][129];
  __shared__ float sqv[128];
  __shared__ float sqp[256];
  __shared__ float teach_s[128][NC];
  __shared__ float numer[64][NC];
  __shared__ float rsum[64];

  const int b = blockIdx.x >> 1;
  const int half = blockIdx.x & 1;
  const int tid = threadIdx.x;
  const int lane = tid & 63;
  const int w = tid >> 6;
  const size_t fbase = (size_t)b * TT * DD;

  for (int idx = tid; idx < TT * NC; idx += 256)
    teach_s[idx / NC][idx % NC] = teach[(size_t)b * TT * NC + idx];

  {
    int row = tid >> 1;
    int kh = (tid & 1) << 9;
    const short* fp = F + fbase + (size_t)row * DD + kh;
    float s = 0.f;
    for (int k = 0; k < 512; k += 8) {
      short8 v = *reinterpret_cast<const short8*>(fp + k);
#pragma unroll
      for (int j = 0; j < 8; ++j) { float x = bf2f(v[j]); s += x * x; }
    }
    sqp[tid] = s;
  }
  __syncthreads();
  if (tid < 128) sqv[tid] = sqp[2 * tid] + sqp[2 * tid + 1];
  __syncthreads();

  f32x4 acc[2][4] = {};
  const int fr = lane & 15;
  const int fk = (lane >> 4) << 3;
  for (int k0 = 0; k0 < DD; k0 += 32) {
#pragma unroll
    for (int i = 0; i < 2; ++i) {
      int idx = tid + (i << 8);
      int row = idx >> 2;
      int kc = (idx & 3) << 3;
      short8 v = *reinterpret_cast<const short8*>(F + fbase + (size_t)row * DD + (k0 + kc));
      *reinterpret_cast<short8*>(&ftile[row][kc]) = v;
    }
    __syncthreads();
    short8 af[2], bfv[4];
#pragma unroll
    for (int mi = 0; mi < 2; ++mi)
      af[mi] = *reinterpret_cast<const short8*>(&ftile[w * 32 + mi * 16 + fr][fk]);
#pragma unroll
    for (int ni = 0; ni < 4; ++ni)
      bfv[ni] = *reinterpret_cast<const short8*>(&ftile[half * 64 + ni * 16 + fr][fk]);
#pragma unroll
    for (int mi = 0; mi < 2; ++mi)
#pragma unroll
      for (int ni = 0; ni < 4; ++ni)
        acc[mi][ni] = __builtin_amdgcn_mfma_f32_16x16x32_bf16(af[mi], bfv[ni], acc[mi][ni], 0, 0, 0);
    __syncthreads();
  }

  const float c0 = cptr[0];
  const int cc = lane & 15;
  const int crr = (lane >> 4) << 2;
#pragma unroll
  for (int mi = 0; mi < 2; ++mi) {
#pragma unroll
    for (int ni = 0; ni < 4; ++ni) {
#pragma unroll
      for (int q = 0; q < 4; ++q) {
        int s_g = w * 32 + mi * 16 + crr + q;
        int tl = ni * 16 + cc;
        int t_g = half * 64 + tl;
        float g = acc[mi][ni][q];
        float d2 = sqv[s_g] + sqv[t_g] - 2.0f * g;
        d2 = fmaxf(d2, EPS_D2_F);
        float dist = sqrtf(sqrtf(d2));
        simsT[tl][s_g] = (s_g < t_g) ? expf(-c0 * dist) : 0.0f;
      }
    }
  }
  __syncthreads();

  const float gam = gptr[0];
  for (int idx = tid; idx < 64 * NC; idx += 256) {
    int tl = idx / NC, c = idx % NC;
    float s = 0.f;
#pragma unroll 4
    for (int si = 0; si < TT; ++si)
      s += simsT[tl][si] * teach_s[si][c];
    float v = EPS_NUMER_F + s;
    numer[tl][c] = (gam == 1.0f) ? v : powf(v, gam);
  }
  __syncthreads();
  if (tid < 64) {
    float s = 0.f;
#pragma unroll
    for (int c = 0; c < NC; ++c) s += numer[tid][c];
    rsum[tid] = s;
  }
  __syncthreads();
  for (int idx = tid; idx < 64 * NC; idx += 256) {
    int tl = idx / NC, c = idx % NC;
    int t_g = half * 64 + tl;
    float v = numer[tl][c] / rsum[tl];
    if (t_g == 0) v = EPS_NUMER_F;
    out[(size_t)b * TT * NC + (size_t)t_g * NC + c] = v;
  }
}

// ---------------------------------------------------------------------------
extern "C" void kernel_launch(void* const* d_in, const int* in_sizes, int n_in,
                              void* d_out, int out_size, void* d_ws, size_t ws_size,
                              hipStream_t stream) {
  const float* data = (const float*)d_in[1];
  const float* teach = (const float*)d_in[2];
  const float* Wfe = (const float*)d_in[3];
  const float* bfe = (const float*)d_in[4];
  const float* cp = (const float*)d_in[5];
  const float* gp = (const float*)d_in[6];
  float* outp = (float*)d_out;

  char* ws = (char*)d_ws;
  short* Wt = (short*)ws;                             // @0:    6.29 MB
  short* F = (short*)(ws + (size_t)8 * 1024 * 1024);  // @8MB:  33.55 MB
  short* Xb = (short*)(ws + (size_t)48 * 1024 * 1024);// @48MB: 100.66 MB

  const size_t need = (size_t)48 * 1024 * 1024 + (size_t)MM * CHW * 2;

  k_transpose_w<<<dim3(DD / 32, CHW / 32), 256, 0, stream>>>(Wfe, Wt);
  if (ws_size >= need) {
    k_convert_x<<<dim3((MM * CHW) / 2048), 256, 0, stream>>>(data, Xb);
    k_gemm_feats<<<dim3((MM / 128) * (DD / 128)), 256, 0, stream>>>(Xb, Wt, bfe, F);
  } else {
    k_gemm_feats_rs<<<dim3((MM / 128) * (DD / 128)), 256, 0, stream>>>(data, Wt, bfe, F);
  }
  k_batch_sims<<<dim3(BB * 2), 256, 0, stream>>>(F, teach, cp, gp, outp);
}

// Round 4
// 186.962 us; speedup vs baseline: 1.5411x; 1.2091x over previous
//
#include <hip/hip_runtime.h>

typedef short short8 __attribute__((ext_vector_type(8)));
typedef short short4v __attribute__((ext_vector_type(4)));
typedef float f32x4 __attribute__((ext_vector_type(4)));

#define EPS_NUMER_F 1e-8f
#define EPS_D2_F 1e-12f

#define BB 128
#define TT 128
#define DD 1024
#define CHW 3072
#define NC 10
#define MM (BB * TT)
#define NT 48              // CHW / 64 K-tiles

#define GLOAD_LDS16(g, l)                                              \
  __builtin_amdgcn_global_load_lds(                                    \
      (const __attribute__((address_space(1))) void*)(g),              \
      (__attribute__((address_space(3))) void*)(l), 16, 0, 0)

static __device__ __forceinline__ short f2bf(float x) {
  unsigned int u = __float_as_uint(x);
  u = (u + 0x7fffu + ((u >> 16) & 1u)) >> 16;
  return (short)u;
}
static __device__ __forceinline__ float bf2f(short x) {
  return __uint_as_float(((unsigned int)(unsigned short)x) << 16);
}

// ---------------------------------------------------------------------------
// X (16384 x 3072 f32) -> Xb (bf16)
// ---------------------------------------------------------------------------
__global__ __launch_bounds__(256) void k_convert_x(const float* __restrict__ X,
                                                   short* __restrict__ Xb) {
  size_t i = ((size_t)blockIdx.x * 256 + threadIdx.x) * 8;
  float4 a = *reinterpret_cast<const float4*>(X + i);
  float4 b = *reinterpret_cast<const float4*>(X + i + 4);
  short8 s;
  s[0] = f2bf(a.x); s[1] = f2bf(a.y); s[2] = f2bf(a.z); s[3] = f2bf(a.w);
  s[4] = f2bf(b.x); s[5] = f2bf(b.y); s[6] = f2bf(b.z); s[7] = f2bf(b.w);
  *reinterpret_cast<short8*>(Xb + i) = s;
}

// ---------------------------------------------------------------------------
// W_fe (3072 x 1024 f32, K x N) -> Wt (1024 x 3072 bf16, N x K)
// ---------------------------------------------------------------------------
__global__ __launch_bounds__(256) void k_transpose_w(const float* __restrict__ W,
                                                     short* __restrict__ Wt) {
  __shared__ float tile[32][33];
  const int n0 = blockIdx.x * 32;
  const int k0 = blockIdx.y * 32;
  const int tx = threadIdx.x & 31;
  const int ty = threadIdx.x >> 5;
#pragma unroll
  for (int i = 0; i < 32; i += 8)
    tile[ty + i][tx] = W[(size_t)(k0 + ty + i) * DD + (n0 + tx)];
  __syncthreads();
#pragma unroll
  for (int i = 0; i < 32; i += 8)
    Wt[(size_t)(n0 + ty + i) * CHW + (k0 + tx)] = f2bf(tile[tx][ty + i]);
}

// ---------------------------------------------------------------------------
// 256x256 8-phase GEMM: F = Xb @ Wt^T + b.  BK=64, 512 thr (8 waves 2Mx4N),
// 2 LDS buffers, counted vmcnt(4), T2 source-swizzle, T5 setprio.
// ---------------------------------------------------------------------------
__global__ __launch_bounds__(512, 2) void k_gemm_8ph(const short* __restrict__ Xb,
                                                     const short* __restrict__ Wt,
                                                     const float* __restrict__ bias,
                                                     short* __restrict__ F) {
  __shared__ short As[2][256 * 64];
  __shared__ short Bs[2][256 * 64];

  // 256 blocks, 8 XCDs, 32 contiguous ids per XCD
  const int bid = blockIdx.x;
  const int id = (bid & 7) * 32 + (bid >> 3);
  const int bm = (id >> 2) << 8;   // M tile (64 tiles)
  const int bn = (id & 3) << 8;    // N tile (4 tiles)

  const int tid = threadIdx.x;
  const int lane = tid & 63;
  const int wid = tid >> 6;        // 0..7
  const int wr = wid >> 2;         // 0..1 -> rows wr*128
  const int wc = wid & 3;          // 0..3 -> cols wc*64

  // staging: lane covers row += lane>>3, source col-slot = (lane&7)^(lane>>3)
  const int srow = lane >> 3;
  const int sslot = (lane & 7) ^ (lane >> 3);
  const short* aSrc = Xb + (size_t)(bm + srow) * CHW + sslot * 8;
  const short* bSrc = Wt + (size_t)(bn + srow) * CHW + sslot * 8;

#define STAGE_A_HALF(T_, h_) do {                                            \
    int base_ = (h_) * 128 + wid * 8;                                        \
    GLOAD_LDS16(aSrc + (size_t)(base_) * CHW + (T_) * 64,                    \
                &As[(T_) & 1][(base_) * 64]);                                \
    GLOAD_LDS16(aSrc + (size_t)(base_ + 64) * CHW + (T_) * 64,              \
                &As[(T_) & 1][(base_ + 64) * 64]);                           \
  } while (0)
#define STAGE_B_HALF(T_, h_) do {                                            \
    int base_ = (h_) * 128 + wid * 8;                                        \
    GLOAD_LDS16(bSrc + (size_t)(base_) * CHW + (T_) * 64,                    \
                &Bs[(T_) & 1][(base_) * 64]);                                \
    GLOAD_LDS16(bSrc + (size_t)(base_ + 64) * CHW + (T_) * 64,              \
                &Bs[(T_) & 1][(base_ + 64) * 64]);                           \
  } while (0)

  // fragment read addressing (swizzled): row&7 == lane&7 for all frags
  const int fr = lane & 15;
  const int sl = lane >> 4;                 // 0..3
  const int slotk0 = (0 + sl) ^ (lane & 7); // kstep 0 slot
  const int slotk1 = (4 + sl) ^ (lane & 7); // kstep 1 slot
  const int arow = wr * 128 + fr;
  const int brow = wc * 64 + fr;

  f32x4 acc[8][4] = {};

  // prologue: B0, A0, B1 (6 half-tiles = 12 loads); wait B0+A0 (vmcnt 4)
  STAGE_B_HALF(0, 0); STAGE_B_HALF(0, 1);
  STAGE_A_HALF(0, 0); STAGE_A_HALF(0, 1);
  STAGE_B_HALF(1, 0); STAGE_B_HALF(1, 1);
  asm volatile("s_waitcnt vmcnt(4)" ::: "memory");
  __builtin_amdgcn_s_barrier();

  for (int T = 0; T < NT; ++T) {
    const int buf = T & 1;
    const short* ab = &As[buf][0];
    const short* bb = &Bs[buf][0];
    short8 bf_[8];
    short8 aq[4];

#define READ_AQ(q_) do {                                                     \
      aq[0] = *(const short8*)(ab + (arow + (2*(q_))    *16)*64 + slotk0*8); \
      aq[1] = *(const short8*)(ab + (arow + (2*(q_))    *16)*64 + slotk1*8); \
      aq[2] = *(const short8*)(ab + (arow + (2*(q_) + 1)*16)*64 + slotk0*8); \
      aq[3] = *(const short8*)(ab + (arow + (2*(q_) + 1)*16)*64 + slotk1*8); \
    } while (0)
#define MFMA16(q_) do {                                                      \
      _Pragma("unroll")                                                      \
      for (int m2 = 0; m2 < 2; ++m2)                                         \
        _Pragma("unroll")                                                    \
        for (int ks = 0; ks < 2; ++ks)                                       \
          _Pragma("unroll")                                                  \
          for (int ni = 0; ni < 4; ++ni)                                     \
            acc[2*(q_)+m2][ni] = __builtin_amdgcn_mfma_f32_16x16x32_bf16(    \
                aq[m2*2+ks], bf_[ni*2+ks], acc[2*(q_)+m2][ni], 0, 0, 0);     \
    } while (0)

    // ---- q0: read all B frags + A quad 0; prefetch A(T+1) h0
#pragma unroll
    for (int ni = 0; ni < 4; ++ni) {
      bf_[ni * 2 + 0] = *(const short8*)(bb + (brow + ni * 16) * 64 + slotk0 * 8);
      bf_[ni * 2 + 1] = *(const short8*)(bb + (brow + ni * 16) * 64 + slotk1 * 8);
    }
    READ_AQ(0);
    if (T + 1 < NT) STAGE_A_HALF(T + 1, 0);
    __builtin_amdgcn_s_barrier();
    __builtin_amdgcn_s_setprio(1);
    MFMA16(0);
    __builtin_amdgcn_s_setprio(0);
    __builtin_amdgcn_s_barrier();

    // ---- q1: A quad 1; prefetch A(T+1) h1
    READ_AQ(1);
    if (T + 1 < NT) STAGE_A_HALF(T + 1, 1);
    __builtin_amdgcn_s_barrier();
    __builtin_amdgcn_s_setprio(1);
    MFMA16(1);
    __builtin_amdgcn_s_setprio(0);
    __builtin_amdgcn_s_barrier();

    // ---- q2: A quad 2; prefetch B(T+2) h0  (Bs[buf] free after q0 barrier)
    READ_AQ(2);
    if (T + 2 < NT) STAGE_B_HALF(T + 2, 0);
    __builtin_amdgcn_s_barrier();
    __builtin_amdgcn_s_setprio(1);
    MFMA16(2);
    __builtin_amdgcn_s_setprio(0);
    __builtin_amdgcn_s_barrier();

    // ---- q3: A quad 3; prefetch B(T+2) h1; counted wait for tile T+1
    READ_AQ(3);
    if (T + 2 < NT) {
      STAGE_B_HALF(T + 2, 1);
      asm volatile("s_waitcnt vmcnt(4)" ::: "memory");
    } else if (T + 1 < NT) {
      asm volatile("s_waitcnt vmcnt(0)" ::: "memory");
    }
    __builtin_amdgcn_s_barrier();
    __builtin_amdgcn_s_setprio(1);
    MFMA16(3);
    __builtin_amdgcn_s_setprio(0);
    __builtin_amdgcn_s_barrier();
  }

  // epilogue: C/D layout col = lane&15, row = (lane>>4)*4 + q
  const int cc = lane & 15;
  const int crr = sl << 2;
#pragma unroll
  for (int ni = 0; ni < 4; ++ni) {
    int col = bn + wc * 64 + ni * 16 + cc;
    float bv = bias[col];
#pragma unroll
    for (int mi = 0; mi < 8; ++mi) {
      int row0 = bm + wr * 128 + mi * 16 + crr;
#pragma unroll
      for (int q = 0; q < 4; ++q)
        F[(size_t)(row0 + q) * DD + col] = f2bf(acc[mi][ni][q] + bv);
    }
  }
#undef READ_AQ
#undef MFMA16
#undef STAGE_A_HALF
#undef STAGE_B_HALF
}

// ---------------------------------------------------------------------------
// Fallback GEMM (reg-staged inline convert) if ws too small for Xb
// ---------------------------------------------------------------------------
__global__ __launch_bounds__(256) void k_gemm_feats_rs(const float* __restrict__ X,
                                                       const short* __restrict__ Wt,
                                                       const float* __restrict__ bias,
                                                       short* __restrict__ F) {
  __shared__ short As[128][40];
  __shared__ short Bs[128][40];
  const int bid = blockIdx.x;
  const int id = (bid & 7) * 128 + (bid >> 3);
  const int bm = (id >> 3) << 7;
  const int bn = (id & 7) << 7;
  const int tid = threadIdx.x;
  const int lane = tid & 63;
  const int wid = tid >> 6;
  const int wr = (wid >> 1) * 64;
  const int wc = (wid & 1) * 64;
  f32x4 acc[4][4] = {};
  const int fr = lane & 15;
  const int fk = (lane >> 4) << 3;
  for (int k0 = 0; k0 < CHW; k0 += 32) {
#pragma unroll
    for (int i = 0; i < 4; ++i) {
      int idx = tid + (i << 8);
      int row = idx >> 3;
      int kc = (idx & 7) << 2;
      float4 v = *reinterpret_cast<const float4*>(X + (size_t)(bm + row) * CHW + (k0 + kc));
      short4v s;
      s[0] = f2bf(v.x); s[1] = f2bf(v.y); s[2] = f2bf(v.z); s[3] = f2bf(v.w);
      *reinterpret_cast<short4v*>(&As[row][kc]) = s;
    }
#pragma unroll
    for (int i = 0; i < 2; ++i) {
      int idx = tid + (i << 8);
      int row = idx >> 2;
      int kc = (idx & 3) << 3;
      short8 v = *reinterpret_cast<const short8*>(Wt + (size_t)(bn + row) * CHW + (k0 + kc));
      *reinterpret_cast<short8*>(&Bs[row][kc]) = v;
    }
    __syncthreads();
    short8 af[4], bfv[4];
#pragma unroll
    for (int mi = 0; mi < 4; ++mi)
      af[mi] = *reinterpret_cast<const short8*>(&As[wr + mi * 16 + fr][fk]);
#pragma unroll
    for (int ni = 0; ni < 4; ++ni)
      bfv[ni] = *reinterpret_cast<const short8*>(&Bs[wc + ni * 16 + fr][fk]);
#pragma unroll
    for (int mi = 0; mi < 4; ++mi)
#pragma unroll
      for (int ni = 0; ni < 4; ++ni)
        acc[mi][ni] = __builtin_amdgcn_mfma_f32_16x16x32_bf16(af[mi], bfv[ni], acc[mi][ni], 0, 0, 0);
    __syncthreads();
  }
  const int cc = lane & 15;
  const int crr = (lane >> 4) << 2;
#pragma unroll
  for (int ni = 0; ni < 4; ++ni) {
    int col = bn + wc + ni * 16 + cc;
    float bv = bias[col];
#pragma unroll
    for (int mi = 0; mi < 4; ++mi) {
      int row0 = bm + wr + mi * 16 + crr;
#pragma unroll
      for (int q = 0; q < 4; ++q)
        F[(size_t)(row0 + q) * DD + col] = f2bf(acc[mi][ni][q] + bv);
    }
  }
}

// ---------------------------------------------------------------------------
// Kernel 3: per (batch, t-half): Gram via MFMA -> d2 -> sims -> causal numer
// -> pow/normalize -> out.
// ---------------------------------------------------------------------------
__global__ __launch_bounds__(256) void k_batch_sims(const short* __restrict__ F,
                                                    const float* __restrict__ teach,
                                                    const float* __restrict__ cptr,
                                                    const float* __restrict__ gptr,
                                                    float* __restrict__ out) {
  __shared__ short ftile[128][40];
  __shared__ float simsT[64][129];
  __shared__ float sqv[128];
  __shared__ float sqp[256];
  __shared__ float teach_s[128][NC];
  __shared__ float numer[64][NC];
  __shared__ float rsum[64];

  const int b = blockIdx.x >> 1;
  const int half = blockIdx.x & 1;
  const int tid = threadIdx.x;
  const int lane = tid & 63;
  const int w = tid >> 6;
  const size_t fbase = (size_t)b * TT * DD;

  for (int idx = tid; idx < TT * NC; idx += 256)
    teach_s[idx / NC][idx % NC] = teach[(size_t)b * TT * NC + idx];

  {
    int row = tid >> 1;
    int kh = (tid & 1) << 9;
    const short* fp = F + fbase + (size_t)row * DD + kh;
    float s = 0.f;
    for (int k = 0; k < 512; k += 8) {
      short8 v = *reinterpret_cast<const short8*>(fp + k);
#pragma unroll
      for (int j = 0; j < 8; ++j) { float x = bf2f(v[j]); s += x * x; }
    }
    sqp[tid] = s;
  }
  __syncthreads();
  if (tid < 128) sqv[tid] = sqp[2 * tid] + sqp[2 * tid + 1];
  __syncthreads();

  f32x4 acc[2][4] = {};
  const int fr = lane & 15;
  const int fk = (lane >> 4) << 3;
  for (int k0 = 0; k0 < DD; k0 += 32) {
#pragma unroll
    for (int i = 0; i < 2; ++i) {
      int idx = tid + (i << 8);
      int row = idx >> 2;
      int kc = (idx & 3) << 3;
      short8 v = *reinterpret_cast<const short8*>(F + fbase + (size_t)row * DD + (k0 + kc));
      *reinterpret_cast<short8*>(&ftile[row][kc]) = v;
    }
    __syncthreads();
    short8 af[2], bfv[4];
#pragma unroll
    for (int mi = 0; mi < 2; ++mi)
      af[mi] = *reinterpret_cast<const short8*>(&ftile[w * 32 + mi * 16 + fr][fk]);
#pragma unroll
    for (int ni = 0; ni < 4; ++ni)
      bfv[ni] = *reinterpret_cast<const short8*>(&ftile[half * 64 + ni * 16 + fr][fk]);
#pragma unroll
    for (int mi = 0; mi < 2; ++mi)
#pragma unroll
      for (int ni = 0; ni < 4; ++ni)
        acc[mi][ni] = __builtin_amdgcn_mfma_f32_16x16x32_bf16(af[mi], bfv[ni], acc[mi][ni], 0, 0, 0);
    __syncthreads();
  }

  const float c0 = cptr[0];
  const int cc = lane & 15;
  const int crr = (lane >> 4) << 2;
#pragma unroll
  for (int mi = 0; mi < 2; ++mi) {
#pragma unroll
    for (int ni = 0; ni < 4; ++ni) {
#pragma unroll
      for (int q = 0; q < 4; ++q) {
        int s_g = w * 32 + mi * 16 + crr + q;
        int tl = ni * 16 + cc;
        int t_g = half * 64 + tl;
        float g = acc[mi][ni][q];
        float d2 = sqv[s_g] + sqv[t_g] - 2.0f * g;
        d2 = fmaxf(d2, EPS_D2_F);
        float dist = sqrtf(sqrtf(d2));
        simsT[tl][s_g] = (s_g < t_g) ? expf(-c0 * dist) : 0.0f;
      }
    }
  }
  __syncthreads();

  const float gam = gptr[0];
  for (int idx = tid; idx < 64 * NC; idx += 256) {
    int tl = idx / NC, c = idx % NC;
    float s = 0.f;
#pragma unroll 4
    for (int si = 0; si < TT; ++si)
      s += simsT[tl][si] * teach_s[si][c];
    float v = EPS_NUMER_F + s;
    numer[tl][c] = (gam == 1.0f) ? v : powf(v, gam);
  }
  __syncthreads();
  if (tid < 64) {
    float s = 0.f;
#pragma unroll
    for (int c = 0; c < NC; ++c) s += numer[tid][c];
    rsum[tid] = s;
  }
  __syncthreads();
  for (int idx = tid; idx < 64 * NC; idx += 256) {
    int tl = idx / NC, c = idx % NC;
    int t_g = half * 64 + tl;
    float v = numer[tl][c] / rsum[tl];
    if (t_g == 0) v = EPS_NUMER_F;
    out[(size_t)b * TT * NC + (size_t)t_g * NC + c] = v;
  }
}

// ---------------------------------------------------------------------------
extern "C" void kernel_launch(void* const* d_in, const int* in_sizes, int n_in,
                              void* d_out, int out_size, void* d_ws, size_t ws_size,
                              hipStream_t stream) {
  const float* data = (const float*)d_in[1];
  const float* teach = (const float*)d_in[2];
  const float* Wfe = (const float*)d_in[3];
  const float* bfe = (const float*)d_in[4];
  const float* cp = (const float*)d_in[5];
  const float* gp = (const float*)d_in[6];
  float* outp = (float*)d_out;

  char* ws = (char*)d_ws;
  short* Wt = (short*)ws;                              // @0:    6.29 MB
  short* F = (short*)(ws + (size_t)8 * 1024 * 1024);   // @8MB:  33.55 MB
  short* Xb = (short*)(ws + (size_t)48 * 1024 * 1024); // @48MB: 100.66 MB

  const size_t need = (size_t)48 * 1024 * 1024 + (size_t)MM * CHW * 2;

  k_transpose_w<<<dim3(DD / 32, CHW / 32), 256, 0, stream>>>(Wfe, Wt);
  if (ws_size >= need) {
    k_convert_x<<<dim3((MM * CHW) / 2048), 256, 0, stream>>>(data, Xb);
    k_gemm_8ph<<<dim3((MM / 256) * (DD / 256)), 512, 0, stream>>>(Xb, Wt, bfe, F);
  } else {
    k_gemm_feats_rs<<<dim3((MM / 128) * (DD / 128)), 256, 0, stream>>>(data, Wt, bfe, F);
  }
  k_batch_sims<<<dim3(BB * 2), 256, 0, stream>>>(F, teach, cp, gp, outp);
}

// Round 5
// 179.411 us; speedup vs baseline: 1.6060x; 1.0421x over previous
//
#include <hip/hip_runtime.h>

typedef short short8 __attribute__((ext_vector_type(8)));
typedef short short4v __attribute__((ext_vector_type(4)));
typedef float f32x4 __attribute__((ext_vector_type(4)));

#define EPS_NUMER_F 1e-8f
#define EPS_D2_F 1e-12f

#define BB 128
#define TT 128
#define DD 1024
#define CHW 3072
#define NC 10
#define MM (BB * TT)
#define NT 48              // CHW / 64 K-tiles

#define GLOAD_LDS16(g, l)                                              \
  __builtin_amdgcn_global_load_lds(                                    \
      (const __attribute__((address_space(1))) void*)(g),              \
      (__attribute__((address_space(3))) void*)(l), 16, 0, 0)

// inline-asm ds_read_b128: compiler sees only a register def, no LDS
// dependence -> no auto vmcnt(0) drain against global_load_lds prefetches.
#define DS_READ_B128(dst_, off_) \
  asm volatile("ds_read_b128 %0, %1" : "=v"(dst_) : "v"(off_))

static __device__ __forceinline__ unsigned lds_addr(const void* p) {
  return (unsigned)(unsigned long long)(const __attribute__((address_space(3))) void*)p;
}

static __device__ __forceinline__ short f2bf(float x) {
  unsigned int u = __float_as_uint(x);
  u = (u + 0x7fffu + ((u >> 16) & 1u)) >> 16;
  return (short)u;
}
static __device__ __forceinline__ float bf2f(short x) {
  return __uint_as_float(((unsigned int)(unsigned short)x) << 16);
}

// ---------------------------------------------------------------------------
// X (16384 x 3072 f32) -> Xb (bf16)
// ---------------------------------------------------------------------------
__global__ __launch_bounds__(256) void k_convert_x(const float* __restrict__ X,
                                                   short* __restrict__ Xb) {
  size_t i = ((size_t)blockIdx.x * 256 + threadIdx.x) * 8;
  float4 a = *reinterpret_cast<const float4*>(X + i);
  float4 b = *reinterpret_cast<const float4*>(X + i + 4);
  short8 s;
  s[0] = f2bf(a.x); s[1] = f2bf(a.y); s[2] = f2bf(a.z); s[3] = f2bf(a.w);
  s[4] = f2bf(b.x); s[5] = f2bf(b.y); s[6] = f2bf(b.z); s[7] = f2bf(b.w);
  *reinterpret_cast<short8*>(Xb + i) = s;
}

// ---------------------------------------------------------------------------
// W_fe (3072 x 1024 f32, K x N) -> Wt (1024 x 3072 bf16, N x K)
// ---------------------------------------------------------------------------
__global__ __launch_bounds__(256) void k_transpose_w(const float* __restrict__ W,
                                                     short* __restrict__ Wt) {
  __shared__ float tile[32][33];
  const int n0 = blockIdx.x * 32;
  const int k0 = blockIdx.y * 32;
  const int tx = threadIdx.x & 31;
  const int ty = threadIdx.x >> 5;
#pragma unroll
  for (int i = 0; i < 32; i += 8)
    tile[ty + i][tx] = W[(size_t)(k0 + ty + i) * DD + (n0 + tx)];
  __syncthreads();
#pragma unroll
  for (int i = 0; i < 32; i += 8)
    Wt[(size_t)(n0 + ty + i) * CHW + (k0 + tx)] = f2bf(tile[tx][ty + i]);
}

// ---------------------------------------------------------------------------
// 256x256 8-phase GEMM: F = Xb @ Wt^T + b.  BK=64, 512 thr (8 waves 2Mx4N),
// 2 LDS buffers, counted vmcnt(4) as the ONLY vmem wait, T2 source-swizzle,
// T5 setprio, inline-asm ds_read_b128 (prevents compiler vmcnt(0) drains).
// ---------------------------------------------------------------------------
__global__ __launch_bounds__(512, 2) void k_gemm_8ph(const short* __restrict__ Xb,
                                                     const short* __restrict__ Wt,
                                                     const float* __restrict__ bias,
                                                     short* __restrict__ F) {
  __shared__ short As[2][256 * 64];
  __shared__ short Bs[2][256 * 64];

  // 256 blocks, 8 XCDs, 32 contiguous ids per XCD
  const int bid = blockIdx.x;
  const int id = (bid & 7) * 32 + (bid >> 3);
  const int bm = (id >> 2) << 8;   // M tile (64 tiles)
  const int bn = (id & 3) << 8;    // N tile (4 tiles)

  const int tid = threadIdx.x;
  const int lane = tid & 63;
  const int wid = tid >> 6;        // 0..7
  const int wr = wid >> 2;         // 0..1 -> rows wr*128
  const int wc = wid & 3;          // 0..3 -> cols wc*64

  // staging: lane covers row += lane>>3, source col-slot = (lane&7)^(lane>>3)
  const int srow = lane >> 3;
  const int sslot = (lane & 7) ^ (lane >> 3);
  const short* aSrc = Xb + (size_t)(bm + srow) * CHW + sslot * 8;
  const short* bSrc = Wt + (size_t)(bn + srow) * CHW + sslot * 8;

#define STAGE_A_HALF(T_, h_) do {                                            \
    int base_ = (h_) * 128 + wid * 8;                                        \
    GLOAD_LDS16(aSrc + (size_t)(base_) * CHW + (T_) * 64,                    \
                &As[(T_) & 1][(base_) * 64]);                                \
    GLOAD_LDS16(aSrc + (size_t)(base_ + 64) * CHW + (T_) * 64,              \
                &As[(T_) & 1][(base_ + 64) * 64]);                           \
  } while (0)
#define STAGE_B_HALF(T_, h_) do {                                            \
    int base_ = (h_) * 128 + wid * 8;                                        \
    GLOAD_LDS16(bSrc + (size_t)(base_) * CHW + (T_) * 64,                    \
                &Bs[(T_) & 1][(base_) * 64]);                                \
    GLOAD_LDS16(bSrc + (size_t)(base_ + 64) * CHW + (T_) * 64,              \
                &Bs[(T_) & 1][(base_ + 64) * 64]);                           \
  } while (0)

  // fragment read addressing (swizzled): byte offsets within a 64KB buffer
  const int fr = lane & 15;
  const int sl = lane >> 4;                 // 0..3
  const int slotk0 = (0 + sl) ^ (lane & 7); // kstep 0 slot
  const int slotk1 = (4 + sl) ^ (lane & 7); // kstep 1 slot
  const int arow = wr * 128 + fr;
  const int brow = wc * 64 + fr;

  const unsigned aBase0 = lds_addr(&As[0][0]);
  const unsigned bBase0 = lds_addr(&Bs[0][0]);

  f32x4 acc[8][4] = {};

  // prologue: B0, A0, B1 (6 half-tiles = 12 loads/wave-pairs); wait B0+A0
  STAGE_B_HALF(0, 0); STAGE_B_HALF(0, 1);
  STAGE_A_HALF(0, 0); STAGE_A_HALF(0, 1);
  STAGE_B_HALF(1, 0); STAGE_B_HALF(1, 1);
  asm volatile("s_waitcnt vmcnt(4)" ::: "memory");
  __builtin_amdgcn_s_barrier();

  for (int T = 0; T < NT; ++T) {
    const unsigned ab = aBase0 + ((T & 1) ? 32768u : 0u);
    const unsigned bb = bBase0 + ((T & 1) ? 32768u : 0u);
    short8 bf_[8];
    short8 aq[4];

#define READ_AQ(q_) do {                                                       \
      DS_READ_B128(aq[0], ab + (unsigned)((arow + (2*(q_))    *16)*128 + slotk0*16)); \
      DS_READ_B128(aq[1], ab + (unsigned)((arow + (2*(q_))    *16)*128 + slotk1*16)); \
      DS_READ_B128(aq[2], ab + (unsigned)((arow + (2*(q_) + 1)*16)*128 + slotk0*16)); \
      DS_READ_B128(aq[3], ab + (unsigned)((arow + (2*(q_) + 1)*16)*128 + slotk1*16)); \
    } while (0)
#define MFMA16(q_) do {                                                      \
      _Pragma("unroll")                                                      \
      for (int m2 = 0; m2 < 2; ++m2)                                         \
        _Pragma("unroll")                                                    \
        for (int ks = 0; ks < 2; ++ks)                                       \
          _Pragma("unroll")                                                  \
          for (int ni = 0; ni < 4; ++ni)                                     \
            acc[2*(q_)+m2][ni] = __builtin_amdgcn_mfma_f32_16x16x32_bf16(    \
                aq[m2*2+ks], bf_[ni*2+ks], acc[2*(q_)+m2][ni], 0, 0, 0);     \
    } while (0)
#define WAIT_LGKM_FENCE() do {                                               \
      asm volatile("s_waitcnt lgkmcnt(0)" ::: "memory");                     \
      __builtin_amdgcn_sched_barrier(0);                                     \
    } while (0)

    // ---- q0: read all B frags + A quad 0; prefetch A(T+1) h0
#pragma unroll
    for (int ni = 0; ni < 4; ++ni) {
      DS_READ_B128(bf_[ni * 2 + 0], bb + (unsigned)((brow + ni * 16) * 128 + slotk0 * 16));
      DS_READ_B128(bf_[ni * 2 + 1], bb + (unsigned)((brow + ni * 16) * 128 + slotk1 * 16));
    }
    READ_AQ(0);
    if (T + 1 < NT) STAGE_A_HALF(T + 1, 0);
    __builtin_amdgcn_s_barrier();
    WAIT_LGKM_FENCE();
    __builtin_amdgcn_s_setprio(1);
    MFMA16(0);
    __builtin_amdgcn_s_setprio(0);
    __builtin_amdgcn_s_barrier();

    // ---- q1: A quad 1; prefetch A(T+1) h1
    READ_AQ(1);
    if (T + 1 < NT) STAGE_A_HALF(T + 1, 1);
    __builtin_amdgcn_s_barrier();
    WAIT_LGKM_FENCE();
    __builtin_amdgcn_s_setprio(1);
    MFMA16(1);
    __builtin_amdgcn_s_setprio(0);
    __builtin_amdgcn_s_barrier();

    // ---- q2: A quad 2; prefetch B(T+2) h0  (Bs[buf] free after q0 barrier)
    READ_AQ(2);
    if (T + 2 < NT) STAGE_B_HALF(T + 2, 0);
    __builtin_amdgcn_s_barrier();
    WAIT_LGKM_FENCE();
    __builtin_amdgcn_s_setprio(1);
    MFMA16(2);
    __builtin_amdgcn_s_setprio(0);
    __builtin_amdgcn_s_barrier();

    // ---- q3: A quad 3; prefetch B(T+2) h1; counted wait for tile T+1
    READ_AQ(3);
    if (T + 2 < NT) {
      STAGE_B_HALF(T + 2, 1);
      asm volatile("s_waitcnt vmcnt(4)" ::: "memory");
    } else if (T + 1 < NT) {
      asm volatile("s_waitcnt vmcnt(0)" ::: "memory");
    }
    __builtin_amdgcn_s_barrier();
    WAIT_LGKM_FENCE();
    __builtin_amdgcn_s_setprio(1);
    MFMA16(3);
    __builtin_amdgcn_s_setprio(0);
    __builtin_amdgcn_s_barrier();
  }

  // epilogue: C/D layout col = lane&15, row = (lane>>4)*4 + q
  const int cc = lane & 15;
  const int crr = sl << 2;
#pragma unroll
  for (int ni = 0; ni < 4; ++ni) {
    int col = bn + wc * 64 + ni * 16 + cc;
    float bv = bias[col];
#pragma unroll
    for (int mi = 0; mi < 8; ++mi) {
      int row0 = bm + wr * 128 + mi * 16 + crr;
#pragma unroll
      for (int q = 0; q < 4; ++q)
        F[(size_t)(row0 + q) * DD + col] = f2bf(acc[mi][ni][q] + bv);
    }
  }
#undef READ_AQ
#undef MFMA16
#undef WAIT_LGKM_FENCE
#undef STAGE_A_HALF
#undef STAGE_B_HALF
}

// ---------------------------------------------------------------------------
// Fallback GEMM (reg-staged inline convert) if ws too small for Xb
// ---------------------------------------------------------------------------
__global__ __launch_bounds__(256) void k_gemm_feats_rs(const float* __restrict__ X,
                                                       const short* __restrict__ Wt,
                                                       const float* __restrict__ bias,
                                                       short* __restrict__ F) {
  __shared__ short As[128][40];
  __shared__ short Bs[128][40];
  const int bid = blockIdx.x;
  const int id = (bid & 7) * 128 + (bid >> 3);
  const int bm = (id >> 3) << 7;
  const int bn = (id & 7) << 7;
  const int tid = threadIdx.x;
  const int lane = tid & 63;
  const int wid = tid >> 6;
  const int wr = (wid >> 1) * 64;
  const int wc = (wid & 1) * 64;
  f32x4 acc[4][4] = {};
  const int fr = lane & 15;
  const int fk = (lane >> 4) << 3;
  for (int k0 = 0; k0 < CHW; k0 += 32) {
#pragma unroll
    for (int i = 0; i < 4; ++i) {
      int idx = tid + (i << 8);
      int row = idx >> 3;
      int kc = (idx & 7) << 2;
      float4 v = *reinterpret_cast<const float4*>(X + (size_t)(bm + row) * CHW + (k0 + kc));
      short4v s;
      s[0] = f2bf(v.x); s[1] = f2bf(v.y); s[2] = f2bf(v.z); s[3] = f2bf(v.w);
      *reinterpret_cast<short4v*>(&As[row][kc]) = s;
    }
#pragma unroll
    for (int i = 0; i < 2; ++i) {
      int idx = tid + (i << 8);
      int row = idx >> 2;
      int kc = (idx & 3) << 3;
      short8 v = *reinterpret_cast<const short8*>(Wt + (size_t)(bn + row) * CHW + (k0 + kc));
      *reinterpret_cast<short8*>(&Bs[row][kc]) = v;
    }
    __syncthreads();
    short8 af[4], bfv[4];
#pragma unroll
    for (int mi = 0; mi < 4; ++mi)
      af[mi] = *reinterpret_cast<const short8*>(&As[wr + mi * 16 + fr][fk]);
#pragma unroll
    for (int ni = 0; ni < 4; ++ni)
      bfv[ni] = *reinterpret_cast<const short8*>(&Bs[wc + ni * 16 + fr][fk]);
#pragma unroll
    for (int mi = 0; mi < 4; ++mi)
#pragma unroll
      for (int ni = 0; ni < 4; ++ni)
        acc[mi][ni] = __builtin_amdgcn_mfma_f32_16x16x32_bf16(af[mi], bfv[ni], acc[mi][ni], 0, 0, 0);
    __syncthreads();
  }
  const int cc = lane & 15;
  const int crr = (lane >> 4) << 2;
#pragma unroll
  for (int ni = 0; ni < 4; ++ni) {
    int col = bn + wc + ni * 16 + cc;
    float bv = bias[col];
#pragma unroll
    for (int mi = 0; mi < 4; ++mi) {
      int row0 = bm + wr + mi * 16 + crr;
#pragma unroll
      for (int q = 0; q < 4; ++q)
        F[(size_t)(row0 + q) * DD + col] = f2bf(acc[mi][ni][q] + bv);
    }
  }
}

// ---------------------------------------------------------------------------
// Kernel 3: per (batch, t-half): Gram via MFMA -> d2 -> sims -> causal numer
// -> pow/normalize -> out.
// ---------------------------------------------------------------------------
__global__ __launch_bounds__(256) void k_batch_sims(const short* __restrict__ F,
                                                    const float* __restrict__ teach,
                                                    const float* __restrict__ cptr,
                                                    const float* __restrict__ gptr,
                                                    float* __restrict__ out) {
  __shared__ short ftile[128][40];
  __shared__ float simsT[64][129];
  __shared__ float sqv[128];
  __shared__ float sqp[256];
  __shared__ float teach_s[128][NC];
  __shared__ float numer[64][NC];
  __shared__ float rsum[64];

  const int b = blockIdx.x >> 1;
  const int half = blockIdx.x & 1;
  const int tid = threadIdx.x;
  const int lane = tid & 63;
  const int w = tid >> 6;
  const size_t fbase = (size_t)b * TT * DD;

  for (int idx = tid; idx < TT * NC; idx += 256)
    teach_s[idx / NC][idx % NC] = teach[(size_t)b * TT * NC + idx];

  {
    int row = tid >> 1;
    int kh = (tid & 1) << 9;
    const short* fp = F + fbase + (size_t)row * DD + kh;
    float s = 0.f;
    for (int k = 0; k < 512; k += 8) {
      short8 v = *reinterpret_cast<const short8*>(fp + k);
#pragma unroll
      for (int j = 0; j < 8; ++j) { float x = bf2f(v[j]); s += x * x; }
    }
    sqp[tid] = s;
  }
  __syncthreads();
  if (tid < 128) sqv[tid] = sqp[2 * tid] + sqp[2 * tid + 1];
  __syncthreads();

  f32x4 acc[2][4] = {};
  const int fr = lane & 15;
  const int fk = (lane >> 4) << 3;
  for (int k0 = 0; k0 < DD; k0 += 32) {
#pragma unroll
    for (int i = 0; i < 2; ++i) {
      int idx = tid + (i << 8);
      int row = idx >> 2;
      int kc = (idx & 3) << 3;
      short8 v = *reinterpret_cast<const short8*>(F + fbase + (size_t)row * DD + (k0 + kc));
      *reinterpret_cast<short8*>(&ftile[row][kc]) = v;
    }
    __syncthreads();
    short8 af[2], bfv[4];
#pragma unroll
    for (int mi = 0; mi < 2; ++mi)
      af[mi] = *reinterpret_cast<const short8*>(&ftile[w * 32 + mi * 16 + fr][fk]);
#pragma unroll
    for (int ni = 0; ni < 4; ++ni)
      bfv[ni] = *reinterpret_cast<const short8*>(&ftile[half * 64 + ni * 16 + fr][fk]);
#pragma unroll
    for (int mi = 0; mi < 2; ++mi)
#pragma unroll
      for (int ni = 0; ni < 4; ++ni)
        acc[mi][ni] = __builtin_amdgcn_mfma_f32_16x16x32_bf16(af[mi], bfv[ni], acc[mi][ni], 0, 0, 0);
    __syncthreads();
  }

  const float c0 = cptr[0];
  const int cc = lane & 15;
  const int crr = (lane >> 4) << 2;
#pragma unroll
  for (int mi = 0; mi < 2; ++mi) {
#pragma unroll
    for (int ni = 0; ni < 4; ++ni) {
#pragma unroll
      for (int q = 0; q < 4; ++q) {
        int s_g = w * 32 + mi * 16 + crr + q;
        int tl = ni * 16 + cc;
        int t_g = half * 64 + tl;
        float g = acc[mi][ni][q];
        float d2 = sqv[s_g] + sqv[t_g] - 2.0f * g;
        d2 = fmaxf(d2, EPS_D2_F);
        float dist = sqrtf(sqrtf(d2));
        simsT[tl][s_g] = (s_g < t_g) ? expf(-c0 * dist) : 0.0f;
      }
    }
  }
  __syncthreads();

  const float gam = gptr[0];
  for (int idx = tid; idx < 64 * NC; idx += 256) {
    int tl = idx / NC, c = idx % NC;
    float s = 0.f;
#pragma unroll 4
    for (int si = 0; si < TT; ++si)
      s += simsT[tl][si] * teach_s[si][c];
    float v = EPS_NUMER_F + s;
    numer[tl][c] = (gam == 1.0f) ? v : powf(v, gam);
  }
  __syncthreads();
  if (tid < 64) {
    float s = 0.f;
#pragma unroll
    for (int c = 0; c < NC; ++c) s += numer[tid][c];
    rsum[tid] = s;
  }
  __syncthreads();
  for (int idx = tid; idx < 64 * NC; idx += 256) {
    int tl = idx / NC, c = idx % NC;
    int t_g = half * 64 + tl;
    float v = numer[tl][c] / rsum[tl];
    if (t_g == 0) v = EPS_NUMER_F;
    out[(size_t)b * TT * NC + (size_t)t_g * NC + c] = v;
  }
}

// ---------------------------------------------------------------------------
extern "C" void kernel_launch(void* const* d_in, const int* in_sizes, int n_in,
                              void* d_out, int out_size, void* d_ws, size_t ws_size,
                              hipStream_t stream) {
  const float* data = (const float*)d_in[1];
  const float* teach = (const float*)d_in[2];
  const float* Wfe = (const float*)d_in[3];
  const float* bfe = (const float*)d_in[4];
  const float* cp = (const float*)d_in[5];
  const float* gp = (const float*)d_in[6];
  float* outp = (float*)d_out;

  char* ws = (char*)d_ws;
  short* Wt = (short*)ws;                              // @0:    6.29 MB
  short* F = (short*)(ws + (size_t)8 * 1024 * 1024);   // @8MB:  33.55 MB
  short* Xb = (short*)(ws + (size_t)48 * 1024 * 1024); // @48MB: 100.66 MB

  const size_t need = (size_t)48 * 1024 * 1024 + (size_t)MM * CHW * 2;

  k_transpose_w<<<dim3(DD / 32, CHW / 32), 256, 0, stream>>>(Wfe, Wt);
  if (ws_size >= need) {
    k_convert_x<<<dim3((MM * CHW) / 2048), 256, 0, stream>>>(data, Xb);
    k_gemm_8ph<<<dim3((MM / 256) * (DD / 256)), 512, 0, stream>>>(Xb, Wt, bfe, F);
  } else {
    k_gemm_feats_rs<<<dim3((MM / 128) * (DD / 128)), 256, 0, stream>>>(data, Wt, bfe, F);
  }
  k_batch_sims<<<dim3(BB * 2), 256, 0, stream>>>(F, teach, cp, gp, outp);
}

// Round 6
// 167.235 us; speedup vs baseline: 1.7229x; 1.0728x over previous
//
#include <hip/hip_runtime.h>

typedef short short8 __attribute__((ext_vector_type(8)));
typedef short short4v __attribute__((ext_vector_type(4)));
typedef float f32x4 __attribute__((ext_vector_type(4)));
typedef unsigned int uint4v __attribute__((ext_vector_type(4)));

#define EPS_NUMER_F 1e-8f
#define EPS_D2_F 1e-12f

#define BB 128
#define TT 128
#define DD 1024
#define CHW 3072
#define NC 10
#define MM (BB * TT)
#define NT 48              // CHW / 64 K-tiles

#define GLOAD_LDS16(g, l)                                              \
  __builtin_amdgcn_global_load_lds(                                    \
      (const __attribute__((address_space(1))) void*)(g),              \
      (__attribute__((address_space(3))) void*)(l), 16, 0, 0)

// inline-asm LDS ops: opaque to compiler's memory model (no forced drains).
// Mutual order guaranteed by volatile; vs builtins pinned by sched_barrier(0).
#define DS_READ_B128(dst_, off_) \
  asm volatile("ds_read_b128 %0, %1" : "=v"(dst_) : "v"(off_))
#define DS_WRITE_B128(off_, val_) \
  asm volatile("ds_write_b128 %0, %1" :: "v"(off_), "v"(val_))

static __device__ __forceinline__ unsigned lds_addr(const void* p) {
  return (unsigned)(unsigned long long)(const __attribute__((address_space(3))) void*)p;
}
static __device__ __forceinline__ unsigned cvt2(float lo, float hi) {
  unsigned r;
  asm("v_cvt_pk_bf16_f32 %0, %1, %2" : "=v"(r) : "v"(lo), "v"(hi));
  return r;
}

static __device__ __forceinline__ short f2bf(float x) {
  unsigned int u = __float_as_uint(x);
  u = (u + 0x7fffu + ((u >> 16) & 1u)) >> 16;
  return (short)u;
}
static __device__ __forceinline__ float bf2f(short x) {
  return __uint_as_float(((unsigned int)(unsigned short)x) << 16);
}

// ---------------------------------------------------------------------------
// W_fe (3072 x 1024 f32, K x N) -> Wt (1024 x 3072 bf16, N x K)
// ---------------------------------------------------------------------------
__global__ __launch_bounds__(256) void k_transpose_w(const float* __restrict__ W,
                                                     short* __restrict__ Wt) {
  __shared__ float tile[32][33];
  const int n0 = blockIdx.x * 32;
  const int k0 = blockIdx.y * 32;
  const int tx = threadIdx.x & 31;
  const int ty = threadIdx.x >> 5;
#pragma unroll
  for (int i = 0; i < 32; i += 8)
    tile[ty + i][tx] = W[(size_t)(k0 + ty + i) * DD + (n0 + tx)];
  __syncthreads();
#pragma unroll
  for (int i = 0; i < 32; i += 8)
    Wt[(size_t)(n0 + ty + i) * CHW + (k0 + tx)] = f2bf(tile[tx][ty + i]);
}

// ---------------------------------------------------------------------------
// Fused 256x256 8-phase GEMM: F = bf16(X) @ Wt^T + b.  BK=64, 512 thr.
// B: global_load_lds (bf16 Wt).  A: reg-staged f32 loads (q0/q1 issue,
// q3 cvt_pk+ds_write after counted vmcnt) -- folds the convert pass away.
// ---------------------------------------------------------------------------
__global__ __launch_bounds__(512, 2) void k_gemm_8ph(const float* __restrict__ X,
                                                     const short* __restrict__ Wt,
                                                     const float* __restrict__ bias,
                                                     short* __restrict__ F) {
  __shared__ short As[2][256 * 64];
  __shared__ short Bs[2][256 * 64];

  // 256 blocks, 8 XCDs, 32 contiguous ids per XCD; ids 4m..4m+3 share bm and
  // are co-resident on one XCD -> A f32 re-reads hit that XCD's L2.
  const int bid = blockIdx.x;
  const int id = (bid & 7) * 32 + (bid >> 3);
  const int bm = (id >> 2) << 8;
  const int bn = (id & 3) << 8;

  const int tid = threadIdx.x;
  const int lane = tid & 63;
  const int wid = tid >> 6;        // 0..7
  const int wr = wid >> 2;         // 0..1 -> rows wr*128
  const int wc = wid & 3;          // 0..3 -> cols wc*64

  // ---- B staging (unchanged): lane row += lane>>3, src slot (lane&7)^(lane>>3)
  const int srow = lane >> 3;
  const int sslot = (lane & 7) ^ (lane >> 3);
  const short* bSrc = Wt + (size_t)(bn + srow) * CHW + sslot * 8;

#define STAGE_B_HALF(T_, h_) do {                                            \
    int base_ = (h_) * 128 + wid * 8;                                        \
    GLOAD_LDS16(bSrc + (size_t)(base_) * CHW + (T_) * 64,                    \
                &Bs[(T_) & 1][(base_) * 64]);                                \
    GLOAD_LDS16(bSrc + (size_t)(base_ + 64) * CHW + (T_) * 64,              \
                &Bs[(T_) & 1][(base_ + 64) * 64]);                           \
  } while (0)

  // ---- A staging (reg): wave covers rows h*128 + wid*16 + j*8 + (lane>>3),
  // global slot s = lane&7 (8 f32), LDS pos p = s ^ (row&7) = (lane&7)^(lane>>3)
  const int arow_st = wid * 16 + (lane >> 3);
  const float* aSrcF = X + (size_t)(bm + arow_st) * CHW + (lane & 7) * 8;
  const unsigned aposb = (unsigned)(((lane & 7) ^ (lane >> 3)) * 16);

#define LOAD_A_HALF(T_, h_, d_) do {                                         \
    const float* p0_ = aSrcF + (size_t)((h_) * 128) * CHW + (T_) * 64;       \
    d_[0] = *reinterpret_cast<const float4*>(p0_);                           \
    d_[1] = *reinterpret_cast<const float4*>(p0_ + 4);                       \
    const float* p1_ = p0_ + (size_t)8 * CHW;                                \
    d_[2] = *reinterpret_cast<const float4*>(p1_);                           \
    d_[3] = *reinterpret_cast<const float4*>(p1_ + 4);                       \
  } while (0)
#define WRITE_A_HALF(T_, h_, d_) do {                                        \
    unsigned ad_ = aWrBase + (((T_) & 1) ? 32768u : 0u) + (h_) * 16384u;     \
    uint4v w0_, w1_;                                                         \
    w0_.x = cvt2(d_[0].x, d_[0].y); w0_.y = cvt2(d_[0].z, d_[0].w);          \
    w0_.z = cvt2(d_[1].x, d_[1].y); w0_.w = cvt2(d_[1].z, d_[1].w);          \
    DS_WRITE_B128(ad_, w0_);                                                 \
    w1_.x = cvt2(d_[2].x, d_[2].y); w1_.y = cvt2(d_[2].z, d_[2].w);          \
    w1_.z = cvt2(d_[3].x, d_[3].y); w1_.w = cvt2(d_[3].z, d_[3].w);          \
    DS_WRITE_B128(ad_ + 1024u, w1_);                                         \
  } while (0)

  // fragment read addressing (swizzled)
  const int fr = lane & 15;
  const int sl = lane >> 4;
  const int slotk0 = (0 + sl) ^ (lane & 7);
  const int slotk1 = (4 + sl) ^ (lane & 7);
  const int arow = wr * 128 + fr;
  const int brow = wc * 64 + fr;

  const unsigned aBase0 = lds_addr(&As[0][0]);
  const unsigned bBase0 = lds_addr(&Bs[0][0]);
  const unsigned aWrBase = aBase0 + (unsigned)(arow_st * 128) + aposb;

  f32x4 acc[8][4] = {};
  float4 ra[4], rb[4];   // held A f32 halves for tile T+1

  // prologue: A0 loads (8), B0 (4), B1 (4); write A0; wait B0; barrier
  LOAD_A_HALF(0, 0, ra);
  LOAD_A_HALF(0, 1, rb);
  STAGE_B_HALF(0, 0); STAGE_B_HALF(0, 1);
  STAGE_B_HALF(1, 0); STAGE_B_HALF(1, 1);
  __builtin_amdgcn_sched_barrier(0);
  WRITE_A_HALF(0, 0, ra);            // compiler inserts precise vmcnt for ra/rb
  WRITE_A_HALF(0, 1, rb);
  asm volatile("s_waitcnt vmcnt(4)");   // B0 landed, B1 in flight
  __builtin_amdgcn_sched_barrier(0);
  asm volatile("s_waitcnt lgkmcnt(0)"); // A0 ds_writes done
  __builtin_amdgcn_sched_barrier(0);
  __builtin_amdgcn_s_barrier();

  for (int T = 0; T < NT; ++T) {
    const unsigned ab = aBase0 + ((T & 1) ? 32768u : 0u);
    const unsigned bb = bBase0 + ((T & 1) ? 32768u : 0u);
    short8 bf_[8];
    short8 aq[4];

#define READ_AQ(q_) do {                                                       \
      DS_READ_B128(aq[0], ab + (unsigned)((arow + (2*(q_))    *16)*128 + slotk0*16)); \
      DS_READ_B128(aq[1], ab + (unsigned)((arow + (2*(q_))    *16)*128 + slotk1*16)); \
      DS_READ_B128(aq[2], ab + (unsigned)((arow + (2*(q_) + 1)*16)*128 + slotk0*16)); \
      DS_READ_B128(aq[3], ab + (unsigned)((arow + (2*(q_) + 1)*16)*128 + slotk1*16)); \
    } while (0)
#define MFMA16(q_) do {                                                      \
      _Pragma("unroll")                                                      \
      for (int m2 = 0; m2 < 2; ++m2)                                         \
        _Pragma("unroll")                                                    \
        for (int ks = 0; ks < 2; ++ks)                                       \
          _Pragma("unroll")                                                  \
          for (int ni = 0; ni < 4; ++ni)                                     \
            acc[2*(q_)+m2][ni] = __builtin_amdgcn_mfma_f32_16x16x32_bf16(    \
                aq[m2*2+ks], bf_[ni*2+ks], acc[2*(q_)+m2][ni], 0, 0, 0);     \
    } while (0)
#define PHASE_MID() do {                                                     \
      __builtin_amdgcn_sched_barrier(0);                                     \
      __builtin_amdgcn_s_barrier();                                          \
      asm volatile("s_waitcnt lgkmcnt(0)");                                  \
      __builtin_amdgcn_sched_barrier(0);                                     \
    } while (0)

    // ---- q0: B frags + A quad 0; issue A(T+1) h0 f32 loads
#pragma unroll
    for (int ni = 0; ni < 4; ++ni) {
      DS_READ_B128(bf_[ni * 2 + 0], bb + (unsigned)((brow + ni * 16) * 128 + slotk0 * 16));
      DS_READ_B128(bf_[ni * 2 + 1], bb + (unsigned)((brow + ni * 16) * 128 + slotk1 * 16));
    }
    READ_AQ(0);
    if (T + 1 < NT) LOAD_A_HALF(T + 1, 0, ra);
    PHASE_MID();
    __builtin_amdgcn_s_setprio(1);
    MFMA16(0);
    __builtin_amdgcn_s_setprio(0);
    __builtin_amdgcn_s_barrier();

    // ---- q1: A quad 1; issue A(T+1) h1 f32 loads
    READ_AQ(1);
    if (T + 1 < NT) LOAD_A_HALF(T + 1, 1, rb);
    PHASE_MID();
    __builtin_amdgcn_s_setprio(1);
    MFMA16(1);
    __builtin_amdgcn_s_setprio(0);
    __builtin_amdgcn_s_barrier();

    // ---- q2: A quad 2; prefetch B(T+2) h0
    READ_AQ(2);
    if (T + 2 < NT) STAGE_B_HALF(T + 2, 0);
    PHASE_MID();
    __builtin_amdgcn_s_setprio(1);
    MFMA16(2);
    __builtin_amdgcn_s_setprio(0);
    __builtin_amdgcn_s_barrier();

    // ---- q3: A quad 3; prefetch B(T+2) h1; counted wait (drains A(T+1)
    // regs + B(T+1) LDS, leaves B(T+2) in flight); cvt+write A(T+1)
    READ_AQ(3);
    if (T + 2 < NT) {
      STAGE_B_HALF(T + 2, 1);
      __builtin_amdgcn_sched_barrier(0);
      asm volatile("s_waitcnt vmcnt(4)");
      __builtin_amdgcn_sched_barrier(0);
    } else if (T + 1 < NT) {
      __builtin_amdgcn_sched_barrier(0);
      asm volatile("s_waitcnt vmcnt(0)");
      __builtin_amdgcn_sched_barrier(0);
    }
    if (T + 1 < NT) {
      WRITE_A_HALF(T + 1, 0, ra);
      WRITE_A_HALF(T + 1, 1, rb);
    }
    PHASE_MID();
    __builtin_amdgcn_s_setprio(1);
    MFMA16(3);
    __builtin_amdgcn_s_setprio(0);
    __builtin_amdgcn_s_barrier();
  }

  // epilogue: C/D layout col = lane&15, row = (lane>>4)*4 + q
  const int cc = lane & 15;
  const int crr = sl << 2;
#pragma unroll
  for (int ni = 0; ni < 4; ++ni) {
    int col = bn + wc * 64 + ni * 16 + cc;
    float bv = bias[col];
#pragma unroll
    for (int mi = 0; mi < 8; ++mi) {
      int row0 = bm + wr * 128 + mi * 16 + crr;
#pragma unroll
      for (int q = 0; q < 4; ++q)
        F[(size_t)(row0 + q) * DD + col] = f2bf(acc[mi][ni][q] + bv);
    }
  }
#undef READ_AQ
#undef MFMA16
#undef PHASE_MID
#undef STAGE_B_HALF
#undef LOAD_A_HALF
#undef WRITE_A_HALF
}

// ---------------------------------------------------------------------------
// Kernel 3: per (batch, t-half): Gram via MFMA -> d2 -> sims -> causal numer
// -> pow/normalize -> out.
// ---------------------------------------------------------------------------
__global__ __launch_bounds__(256) void k_batch_sims(const short* __restrict__ F,
                                                    const float* __restrict__ teach,
                                                    const float* __restrict__ cptr,
                                                    const float* __restrict__ gptr,
                                                    float* __restrict__ out) {
  __shared__ short ftile[128][40];
  __shared__ float simsT[64][129];
  __shared__ float sqv[128];
  __shared__ float sqp[256];
  __shared__ float teach_s[128][NC];
  __shared__ float numer[64][NC];
  __shared__ float rsum[64];

  const int b = blockIdx.x >> 1;
  const int half = blockIdx.x & 1;
  const int tid = threadIdx.x;
  const int lane = tid & 63;
  const int w = tid >> 6;
  const size_t fbase = (size_t)b * TT * DD;

  for (int idx = tid; idx < TT * NC; idx += 256)
    teach_s[idx / NC][idx % NC] = teach[(size_t)b * TT * NC + idx];

  {
    int row = tid >> 1;
    int kh = (tid & 1) << 9;
    const short* fp = F + fbase + (size_t)row * DD + kh;
    float s = 0.f;
    for (int k = 0; k < 512; k += 8) {
      short8 v = *reinterpret_cast<const short8*>(fp + k);
#pragma unroll
      for (int j = 0; j < 8; ++j) { float x = bf2f(v[j]); s += x * x; }
    }
    sqp[tid] = s;
  }
  __syncthreads();
  if (tid < 128) sqv[tid] = sqp[2 * tid] + sqp[2 * tid + 1];
  __syncthreads();

  f32x4 acc[2][4] = {};
  const int fr = lane & 15;
  const int fk = (lane >> 4) << 3;
  for (int k0 = 0; k0 < DD; k0 += 32) {
#pragma unroll
    for (int i = 0; i < 2; ++i) {
      int idx = tid + (i << 8);
      int row = idx >> 2;
      int kc = (idx & 3) << 3;
      short8 v = *reinterpret_cast<const short8*>(F + fbase + (size_t)row * DD + (k0 + kc));
      *reinterpret_cast<short8*>(&ftile[row][kc]) = v;
    }
    __syncthreads();
    short8 af[2], bfv[4];
#pragma unroll
    for (int mi = 0; mi < 2; ++mi)
      af[mi] = *reinterpret_cast<const short8*>(&ftile[w * 32 + mi * 16 + fr][fk]);
#pragma unroll
    for (int ni = 0; ni < 4; ++ni)
      bfv[ni] = *reinterpret_cast<const short8*>(&ftile[half * 64 + ni * 16 + fr][fk]);
#pragma unroll
    for (int mi = 0; mi < 2; ++mi)
#pragma unroll
      for (int ni = 0; ni < 4; ++ni)
        acc[mi][ni] = __builtin_amdgcn_mfma_f32_16x16x32_bf16(af[mi], bfv[ni], acc[mi][ni], 0, 0, 0);
    __syncthreads();
  }

  const float c0 = cptr[0];
  const int cc = lane & 15;
  const int crr = (lane >> 4) << 2;
#pragma unroll
  for (int mi = 0; mi < 2; ++mi) {
#pragma unroll
    for (int ni = 0; ni < 4; ++ni) {
#pragma unroll
      for (int q = 0; q < 4; ++q) {
        int s_g = w * 32 + mi * 16 + crr + q;
        int tl = ni * 16 + cc;
        int t_g = half * 64 + tl;
        float g = acc[mi][ni][q];
        float d2 = sqv[s_g] + sqv[t_g] - 2.0f * g;
        d2 = fmaxf(d2, EPS_D2_F);
        float dist = sqrtf(sqrtf(d2));
        simsT[tl][s_g] = (s_g < t_g) ? expf(-c0 * dist) : 0.0f;
      }
    }
  }
  __syncthreads();

  const float gam = gptr[0];
  for (int idx = tid; idx < 64 * NC; idx += 256) {
    int tl = idx / NC, c = idx % NC;
    float s = 0.f;
#pragma unroll 4
    for (int si = 0; si < TT; ++si)
      s += simsT[tl][si] * teach_s[si][c];
    float v = EPS_NUMER_F + s;
    numer[tl][c] = (gam == 1.0f) ? v : powf(v, gam);
  }
  __syncthreads();
  if (tid < 64) {
    float s = 0.f;
#pragma unroll
    for (int c = 0; c < NC; ++c) s += numer[tid][c];
    rsum[tid] = s;
  }
  __syncthreads();
  for (int idx = tid; idx < 64 * NC; idx += 256) {
    int tl = idx / NC, c = idx % NC;
    int t_g = half * 64 + tl;
    float v = numer[tl][c] / rsum[tl];
    if (t_g == 0) v = EPS_NUMER_F;
    out[(size_t)b * TT * NC + (size_t)t_g * NC + c] = v;
  }
}

// ---------------------------------------------------------------------------
extern "C" void kernel_launch(void* const* d_in, const int* in_sizes, int n_in,
                              void* d_out, int out_size, void* d_ws, size_t ws_size,
                              hipStream_t stream) {
  const float* data = (const float*)d_in[1];
  const float* teach = (const float*)d_in[2];
  const float* Wfe = (const float*)d_in[3];
  const float* bfe = (const float*)d_in[4];
  const float* cp = (const float*)d_in[5];
  const float* gp = (const float*)d_in[6];
  float* outp = (float*)d_out;

  char* ws = (char*)d_ws;
  short* Wt = (short*)ws;                             // @0:   6.29 MB
  short* F = (short*)(ws + (size_t)8 * 1024 * 1024);  // @8MB: 33.55 MB

  k_transpose_w<<<dim3(DD / 32, CHW / 32), 256, 0, stream>>>(Wfe, Wt);
  k_gemm_8ph<<<dim3((MM / 256) * (DD / 256)), 512, 0, stream>>>(data, Wt, bfe, F);
  k_batch_sims<<<dim3(BB * 2), 256, 0, stream>>>(F, teach, cp, gp, outp);
}

// Round 7
// 146.678 us; speedup vs baseline: 1.9644x; 1.1402x over previous
//
#include <hip/hip_runtime.h>

typedef short short8 __attribute__((ext_vector_type(8)));
typedef float f32x4 __attribute__((ext_vector_type(4)));
typedef unsigned int uint4v __attribute__((ext_vector_type(4)));

#define EPS_NUMER_F 1e-8f
#define EPS_D2_F 1e-12f

#define BB 128
#define TT 128
#define DD 1024
#define CHW 3072
#define NC 10
#define MM (BB * TT)
#define NT 48              // CHW / 64 K-tiles

#define GLOAD_LDS16(g, l)                                              \
  __builtin_amdgcn_global_load_lds(                                    \
      (const __attribute__((address_space(1))) void*)(g),              \
      (__attribute__((address_space(3))) void*)(l), 16, 0, 0)

// inline-asm LDS ops: opaque to compiler's memory model (no forced drains).
#define DS_READ_B128(dst_, off_) \
  asm volatile("ds_read_b128 %0, %1" : "=v"(dst_) : "v"(off_))
#define DS_WRITE_B128(off_, val_) \
  asm volatile("ds_write_b128 %0, %1" :: "v"(off_), "v"(val_))

// inline-asm global load, SADDR form: vmcnt-only (never lgkmcnt), scheduled
// entirely by our explicit counted s_waitcnt ledger.
#define GLB_LOAD_X4(dst_, voff_, imm_) \
  asm volatile("global_load_dwordx4 %0, %1, %2 offset:" #imm_ \
               : "=v"(dst_) : "v"(voff_), "s"(xbase))

static __device__ __forceinline__ unsigned lds_addr(const void* p) {
  return (unsigned)(unsigned long long)(const __attribute__((address_space(3))) void*)p;
}
static __device__ __forceinline__ unsigned cvt2(float lo, float hi) {
  unsigned r;
  asm("v_cvt_pk_bf16_f32 %0, %1, %2" : "=v"(r) : "v"(lo), "v"(hi));
  return r;
}

static __device__ __forceinline__ short f2bf(float x) {
  unsigned int u = __float_as_uint(x);
  u = (u + 0x7fffu + ((u >> 16) & 1u)) >> 16;
  return (short)u;
}
static __device__ __forceinline__ float bf2f(short x) {
  return __uint_as_float(((unsigned int)(unsigned short)x) << 16);
}

// ---------------------------------------------------------------------------
// W_fe (3072 x 1024 f32, K x N) -> Wt (1024 x 3072 bf16, N x K)
// ---------------------------------------------------------------------------
__global__ __launch_bounds__(256) void k_transpose_w(const float* __restrict__ W,
                                                     short* __restrict__ Wt) {
  __shared__ float tile[32][33];
  const int n0 = blockIdx.x * 32;
  const int k0 = blockIdx.y * 32;
  const int tx = threadIdx.x & 31;
  const int ty = threadIdx.x >> 5;
#pragma unroll
  for (int i = 0; i < 32; i += 8)
    tile[ty + i][tx] = W[(size_t)(k0 + ty + i) * DD + (n0 + tx)];
  __syncthreads();
#pragma unroll
  for (int i = 0; i < 32; i += 8)
    Wt[(size_t)(n0 + ty + i) * CHW + (k0 + tx)] = f2bf(tile[tx][ty + i]);
}

// ---------------------------------------------------------------------------
// Fused 256x256 8-phase GEMM: F = bf16(X) @ Wt^T + b.  BK=64, 512 thr.
// B: global_load_lds.  A: asm global_load_dwordx4 (vmcnt-only) issued q0/q1,
// cvt_pk+ds_write split across q2 (h0, vmcnt(6)) and q3 (h1, vmcnt(4)).
// ---------------------------------------------------------------------------
__global__ __launch_bounds__(512, 2) void k_gemm_8ph(const float* __restrict__ X,
                                                     const short* __restrict__ Wt,
                                                     const float* __restrict__ bias,
                                                     short* __restrict__ F) {
  __shared__ short As[2][256 * 64];
  __shared__ short Bs[2][256 * 64];

  // 256 blocks, 8 XCDs; ids 4m..4m+3 share bm on one XCD (A L2 reuse)
  const int bid = blockIdx.x;
  const int id = (bid & 7) * 32 + (bid >> 3);
  const int bm = (id >> 2) << 8;
  const int bn = (id & 3) << 8;

  const int tid = threadIdx.x;
  const int lane = tid & 63;
  const int wid = tid >> 6;
  const int wr = wid >> 2;
  const int wc = wid & 3;

  // ---- B staging
  const int srow = lane >> 3;
  const int sslot = (lane & 7) ^ (lane >> 3);
  const short* bSrc = Wt + (size_t)(bn + srow) * CHW + sslot * 8;

#define STAGE_B_HALF(T_, h_) do {                                            \
    int base_ = (h_) * 128 + wid * 8;                                        \
    GLOAD_LDS16(bSrc + (size_t)(base_) * CHW + (T_) * 64,                    \
                &Bs[(T_) & 1][(base_) * 64]);                                \
    GLOAD_LDS16(bSrc + (size_t)(base_ + 64) * CHW + (T_) * 64,              \
                &Bs[(T_) & 1][(base_ + 64) * 64]);                           \
  } while (0)

  // ---- A staging: rows h*128 + wid*16 + jr + (lane>>3), jr in {0,8};
  // global slot lane&7 (8 f32 = 32B); LDS slot (lane&7)^(lane>>3) (swizzle).
  const int arow_st = wid * 16 + (lane >> 3);
  const unsigned long long xbase = (unsigned long long)X;
  unsigned voff[4];   // (h,jr) = (0,0),(0,8),(1,0),(1,8); advance +256B/tile
#pragma unroll
  for (int h = 0; h < 2; ++h)
#pragma unroll
    for (int j = 0; j < 2; ++j)
      voff[h * 2 + j] = (unsigned)(((bm + h * 128 + j * 8 + arow_st) * (size_t)CHW
                                    + (lane & 7) * 8) * 4);
  const unsigned aposb = (unsigned)(((lane & 7) ^ (lane >> 3)) * 16);

  f32x4 ra[4], rb[4];  // h0: ra = {r0a,r0b,r8a,r8b}; h1: rb

#define LOAD_A_H0() do {                                                     \
    GLB_LOAD_X4(ra[0], voff[0], 0);  GLB_LOAD_X4(ra[1], voff[0], 16);        \
    GLB_LOAD_X4(ra[2], voff[1], 0);  GLB_LOAD_X4(ra[3], voff[1], 16);        \
  } while (0)
#define LOAD_A_H1() do {                                                     \
    GLB_LOAD_X4(rb[0], voff[2], 0);  GLB_LOAD_X4(rb[1], voff[2], 16);        \
    GLB_LOAD_X4(rb[2], voff[3], 0);  GLB_LOAD_X4(rb[3], voff[3], 16);        \
  } while (0)
#define ADV_A() do { voff[0] += 256; voff[1] += 256; voff[2] += 256; voff[3] += 256; } while (0)
#define WRITE_A_HALF(T_, h_, d_) do {                                        \
    unsigned ad_ = aWrBase + (((T_) & 1) ? 32768u : 0u) + (h_) * 16384u;     \
    uint4v w0_, w1_;                                                         \
    w0_.x = cvt2(d_[0].x, d_[0].y); w0_.y = cvt2(d_[0].z, d_[0].w);          \
    w0_.z = cvt2(d_[1].x, d_[1].y); w0_.w = cvt2(d_[1].z, d_[1].w);          \
    DS_WRITE_B128(ad_, w0_);                                                 \
    w1_.x = cvt2(d_[2].x, d_[2].y); w1_.y = cvt2(d_[2].z, d_[2].w);          \
    w1_.z = cvt2(d_[3].x, d_[3].y); w1_.w = cvt2(d_[3].z, d_[3].w);          \
    DS_WRITE_B128(ad_ + 1024u, w1_);                                         \
  } while (0)

  // fragment read addressing (swizzled)
  const int fr = lane & 15;
  const int sl = lane >> 4;
  const int slotk0 = (0 + sl) ^ (lane & 7);
  const int slotk1 = (4 + sl) ^ (lane & 7);
  const int arow = wr * 128 + fr;
  const int brow = wc * 64 + fr;

  const unsigned aBase0 = lds_addr(&As[0][0]);
  const unsigned bBase0 = lds_addr(&Bs[0][0]);
  const unsigned aWrBase = aBase0 + (unsigned)(arow_st * 128) + aposb;

  f32x4 acc[8][4] = {};

  // prologue: A(0) loads, B(0)+B(1) stage; vmcnt(4) drains A(0)+B(0);
  // write A(0); lgkm; barrier.  Then advance voffs so loop tile T loads A(T+1).
  LOAD_A_H0();
  LOAD_A_H1();
  ADV_A();
  STAGE_B_HALF(0, 0); STAGE_B_HALF(0, 1);
  STAGE_B_HALF(1, 0); STAGE_B_HALF(1, 1);
  __builtin_amdgcn_sched_barrier(0);
  asm volatile("s_waitcnt vmcnt(4)");
  __builtin_amdgcn_sched_barrier(0);
  WRITE_A_HALF(0, 0, ra);
  WRITE_A_HALF(0, 1, rb);
  asm volatile("s_waitcnt lgkmcnt(0)");
  __builtin_amdgcn_sched_barrier(0);
  __builtin_amdgcn_s_barrier();

  for (int T = 0; T < NT; ++T) {
    const unsigned ab = aBase0 + ((T & 1) ? 32768u : 0u);
    const unsigned bb = bBase0 + ((T & 1) ? 32768u : 0u);
    short8 bf_[8];
    short8 aq[4];

#define READ_AQ(q_) do {                                                       \
      DS_READ_B128(aq[0], ab + (unsigned)((arow + (2*(q_))    *16)*128 + slotk0*16)); \
      DS_READ_B128(aq[1], ab + (unsigned)((arow + (2*(q_))    *16)*128 + slotk1*16)); \
      DS_READ_B128(aq[2], ab + (unsigned)((arow + (2*(q_) + 1)*16)*128 + slotk0*16)); \
      DS_READ_B128(aq[3], ab + (unsigned)((arow + (2*(q_) + 1)*16)*128 + slotk1*16)); \
    } while (0)
#define MFMA16(q_) do {                                                      \
      _Pragma("unroll")                                                      \
      for (int m2 = 0; m2 < 2; ++m2)                                         \
        _Pragma("unroll")                                                    \
        for (int ks = 0; ks < 2; ++ks)                                       \
          _Pragma("unroll")                                                  \
          for (int ni = 0; ni < 4; ++ni)                                     \
            acc[2*(q_)+m2][ni] = __builtin_amdgcn_mfma_f32_16x16x32_bf16(    \
                aq[m2*2+ks], bf_[ni*2+ks], acc[2*(q_)+m2][ni], 0, 0, 0);     \
    } while (0)
#define PHASE_MID() do {                                                     \
      __builtin_amdgcn_sched_barrier(0);                                     \
      __builtin_amdgcn_s_barrier();                                          \
      asm volatile("s_waitcnt lgkmcnt(0)");                                  \
      __builtin_amdgcn_sched_barrier(0);                                     \
    } while (0)

    // ---- q0: issue A(T+1)h0; B frags + A quad 0
    if (T + 1 < NT) LOAD_A_H0();
#pragma unroll
    for (int ni = 0; ni < 4; ++ni) {
      DS_READ_B128(bf_[ni * 2 + 0], bb + (unsigned)((brow + ni * 16) * 128 + slotk0 * 16));
      DS_READ_B128(bf_[ni * 2 + 1], bb + (unsigned)((brow + ni * 16) * 128 + slotk1 * 16));
    }
    READ_AQ(0);
    PHASE_MID();
    __builtin_amdgcn_s_setprio(1);
    MFMA16(0);
    __builtin_amdgcn_s_setprio(0);
    __builtin_amdgcn_s_barrier();

    // ---- q1: issue A(T+1)h1; A quad 1
    if (T + 1 < NT) LOAD_A_H1();
    ADV_A();
    READ_AQ(1);
    PHASE_MID();
    __builtin_amdgcn_s_setprio(1);
    MFMA16(1);
    __builtin_amdgcn_s_setprio(0);
    __builtin_amdgcn_s_barrier();

    // ---- q2: A quad 2; stage B(T+2)h0; counted drain of A(T+1)h0 (+B(T+1));
    // cvt+write A(T+1)h0
    READ_AQ(2);
    if (T + 2 < NT) {
      STAGE_B_HALF(T + 2, 0);
      __builtin_amdgcn_sched_barrier(0);
      asm volatile("s_waitcnt vmcnt(6)");
      __builtin_amdgcn_sched_barrier(0);
    } else if (T + 1 < NT) {
      __builtin_amdgcn_sched_barrier(0);
      asm volatile("s_waitcnt vmcnt(4)");
      __builtin_amdgcn_sched_barrier(0);
    }
    if (T + 1 < NT) WRITE_A_HALF(T + 1, 0, ra);
    PHASE_MID();
    __builtin_amdgcn_s_setprio(1);
    MFMA16(2);
    __builtin_amdgcn_s_setprio(0);
    __builtin_amdgcn_s_barrier();

    // ---- q3: A quad 3; stage B(T+2)h1; counted drain of A(T+1)h1
    // (leaves B(T+2) in flight); cvt+write A(T+1)h1
    READ_AQ(3);
    if (T + 2 < NT) {
      STAGE_B_HALF(T + 2, 1);
      __builtin_amdgcn_sched_barrier(0);
      asm volatile("s_waitcnt vmcnt(4)");
      __builtin_amdgcn_sched_barrier(0);
    } else if (T + 1 < NT) {
      __builtin_amdgcn_sched_barrier(0);
      asm volatile("s_waitcnt vmcnt(0)");
      __builtin_amdgcn_sched_barrier(0);
    }
    if (T + 1 < NT) WRITE_A_HALF(T + 1, 1, rb);
    PHASE_MID();
    __builtin_amdgcn_s_setprio(1);
    MFMA16(3);
    __builtin_amdgcn_s_setprio(0);
    __builtin_amdgcn_s_barrier();
  }

  // epilogue
  const int cc = lane & 15;
  const int crr = sl << 2;
#pragma unroll
  for (int ni = 0; ni < 4; ++ni) {
    int col = bn + wc * 64 + ni * 16 + cc;
    float bv = bias[col];
#pragma unroll
    for (int mi = 0; mi < 8; ++mi) {
      int row0 = bm + wr * 128 + mi * 16 + crr;
#pragma unroll
      for (int q = 0; q < 4; ++q)
        F[(size_t)(row0 + q) * DD + col] = f2bf(acc[mi][ni][q] + bv);
    }
  }
#undef READ_AQ
#undef MFMA16
#undef PHASE_MID
#undef STAGE_B_HALF
}

// ---------------------------------------------------------------------------
// Kernel 3: per (batch, t-half): Gram via MFMA -> d2 -> sims -> causal numer
// -> pow/normalize -> out.
// ---------------------------------------------------------------------------
__global__ __launch_bounds__(256) void k_batch_sims(const short* __restrict__ F,
                                                    const float* __restrict__ teach,
                                                    const float* __restrict__ cptr,
                                                    const float* __restrict__ gptr,
                                                    float* __restrict__ out) {
  __shared__ short ftile[128][40];
  __shared__ float simsT[64][129];
  __shared__ float sqv[128];
  __shared__ float sqp[256];
  __shared__ float teach_s[128][NC];
  __shared__ float numer[64][NC];
  __shared__ float rsum[64];

  const int b = blockIdx.x >> 1;
  const int half = blockIdx.x & 1;
  const int tid = threadIdx.x;
  const int lane = tid & 63;
  const int w = tid >> 6;
  const size_t fbase = (size_t)b * TT * DD;

  for (int idx = tid; idx < TT * NC; idx += 256)
    teach_s[idx / NC][idx % NC] = teach[(size_t)b * TT * NC + idx];

  {
    int row = tid >> 1;
    int kh = (tid & 1) << 9;
    const short* fp = F + fbase + (size_t)row * DD + kh;
    float s = 0.f;
    for (int k = 0; k < 512; k += 8) {
      short8 v = *reinterpret_cast<const short8*>(fp + k);
#pragma unroll
      for (int j = 0; j < 8; ++j) { float x = bf2f(v[j]); s += x * x; }
    }
    sqp[tid] = s;
  }
  __syncthreads();
  if (tid < 128) sqv[tid] = sqp[2 * tid] + sqp[2 * tid + 1];
  __syncthreads();

  f32x4 acc[2][4] = {};
  const int fr = lane & 15;
  const int fk = (lane >> 4) << 3;
  for (int k0 = 0; k0 < DD; k0 += 32) {
#pragma unroll
    for (int i = 0; i < 2; ++i) {
      int idx = tid + (i << 8);
      int row = idx >> 2;
      int kc = (idx & 3) << 3;
      short8 v = *reinterpret_cast<const short8*>(F + fbase + (size_t)row * DD + (k0 + kc));
      *reinterpret_cast<short8*>(&ftile[row][kc]) = v;
    }
    __syncthreads();
    short8 af[2], bfv[4];
#pragma unroll
    for (int mi = 0; mi < 2; ++mi)
      af[mi] = *reinterpret_cast<const short8*>(&ftile[w * 32 + mi * 16 + fr][fk]);
#pragma unroll
    for (int ni = 0; ni < 4; ++ni)
      bfv[ni] = *reinterpret_cast<const short8*>(&ftile[half * 64 + ni * 16 + fr][fk]);
#pragma unroll
    for (int mi = 0; mi < 2; ++mi)
#pragma unroll
      for (int ni = 0; ni < 4; ++ni)
        acc[mi][ni] = __builtin_amdgcn_mfma_f32_16x16x32_bf16(af[mi], bfv[ni], acc[mi][ni], 0, 0, 0);
    __syncthreads();
  }

  const float c0 = cptr[0];
  const int cc = lane & 15;
  const int crr = (lane >> 4) << 2;
#pragma unroll
  for (int mi = 0; mi < 2; ++mi) {
#pragma unroll
    for (int ni = 0; ni < 4; ++ni) {
#pragma unroll
      for (int q = 0; q < 4; ++q) {
        int s_g = w * 32 + mi * 16 + crr + q;
        int tl = ni * 16 + cc;
        int t_g = half * 64 + tl;
        float g = acc[mi][ni][q];
        float d2 = sqv[s_g] + sqv[t_g] - 2.0f * g;
        d2 = fmaxf(d2, EPS_D2_F);
        float dist = sqrtf(sqrtf(d2));
        simsT[tl][s_g] = (s_g < t_g) ? expf(-c0 * dist) : 0.0f;
      }
    }
  }
  __syncthreads();

  const float gam = gptr[0];
  for (int idx = tid; idx < 64 * NC; idx += 256) {
    int tl = idx / NC, c = idx % NC;
    float s = 0.f;
#pragma unroll 4
    for (int si = 0; si < TT; ++si)
      s += simsT[tl][si] * teach_s[si][c];
    float v = EPS_NUMER_F + s;
    numer[tl][c] = (gam == 1.0f) ? v : powf(v, gam);
  }
  __syncthreads();
  if (tid < 64) {
    float s = 0.f;
#pragma unroll
    for (int c = 0; c < NC; ++c) s += numer[tid][c];
    rsum[tid] = s;
  }
  __syncthreads();
  for (int idx = tid; idx < 64 * NC; idx += 256) {
    int tl = idx / NC, c = idx % NC;
    int t_g = half * 64 + tl;
    float v = numer[tl][c] / rsum[tl];
    if (t_g == 0) v = EPS_NUMER_F;
    out[(size_t)b * TT * NC + (size_t)t_g * NC + c] = v;
  }
}

// ---------------------------------------------------------------------------
extern "C" void kernel_launch(void* const* d_in, const int* in_sizes, int n_in,
                              void* d_out, int out_size, void* d_ws, size_t ws_size,
                              hipStream_t stream) {
  const float* data = (const float*)d_in[1];
  const float* teach = (const float*)d_in[2];
  const float* Wfe = (const float*)d_in[3];
  const float* bfe = (const float*)d_in[4];
  const float* cp = (const float*)d_in[5];
  const float* gp = (const float*)d_in[6];
  float* outp = (float*)d_out;

  char* ws = (char*)d_ws;
  short* Wt = (short*)ws;                             // @0:   6.29 MB
  short* F = (short*)(ws + (size_t)8 * 1024 * 1024);  // @8MB: 33.55 MB

  k_transpose_w<<<dim3(DD / 32, CHW / 32), 256, 0, stream>>>(Wfe, Wt);
  k_gemm_8ph<<<dim3((MM / 256) * (DD / 256)), 512, 0, stream>>>(data, Wt, bfe, F);
  k_batch_sims<<<dim3(BB * 2), 256, 0, stream>>>(F, teach, cp, gp, outp);
}